// Round 8
// baseline (181.398 us; speedup 1.0000x reference)
//
#include <hip/hip_runtime.h>
#include <hip/hip_bf16.h>
#include <hip/hip_fp16.h>

#define CHUNK 4096       // edges per histogram/scatter block
#define BCAP 64          // bucket capacity per node (deg ~ Poisson(16))

typedef _Float16 half8 __attribute__((ext_vector_type(8)));
typedef float floatx4 __attribute__((ext_vector_type(4)));

__device__ __forceinline__ float2 h2f(int u)
{
    __half2 h = *reinterpret_cast<__half2*>(&u);
    return __half22float2(h);
}

// ---------------------------------------------------------------------------
// MFMA fused GEMM: [Q|K|V|S] = X[n][64] @ W(64 x 4*HD) + b, per 64-node tile.
// Block = 256 thr / 4 waves; wave w owns matrix w (q,k,v,s). K=64, two k-steps.
//   q -> Q (f32, pre-scaled by 1/sqrt(32)); s -> S (f32)
//   k,v -> KV interleaved fp16: KV[node*2*HD + 2*jj + {0,1}]
// ---------------------------------------------------------------------------
template <int HD>   // 64 (layer1) or 32 (layer2)
__global__ __launch_bounds__(256) void gemm_mfma(
    const float* __restrict__ X, int n,
    const float* __restrict__ W0, const float* __restrict__ W1,
    const float* __restrict__ W2, const float* __restrict__ W3,
    const float* __restrict__ B0, const float* __restrict__ B1,
    const float* __restrict__ B2, const float* __restrict__ B3,
    float* __restrict__ Q, float* __restrict__ S, __half* __restrict__ KV)
{
    constexpr int NTW = HD / 16;
    const float qscale = 0.17677669529663687f;  // 1/sqrt(32)

    __shared__ _Float16 A_lds[64][72];
    __shared__ _Float16 B_lds[4 * HD][72];

    const int tid = threadIdx.x;
    const int n0 = blockIdx.x * 64;

    {
        const int row = tid >> 2;
        const int cb  = (tid & 3) * 16;
        const int gnode = n0 + row;
        if (gnode < n) {
            const float4* xg = reinterpret_cast<const float4*>(X + (size_t)gnode * 64 + cb);
#pragma unroll
            for (int t = 0; t < 4; ++t) {
                const float4 v = xg[t];
                A_lds[row][cb + 4 * t + 0] = (_Float16)v.x;
                A_lds[row][cb + 4 * t + 1] = (_Float16)v.y;
                A_lds[row][cb + 4 * t + 2] = (_Float16)v.z;
                A_lds[row][cb + 4 * t + 3] = (_Float16)v.w;
            }
        } else {
#pragma unroll
            for (int t = 0; t < 16; ++t) A_lds[row][cb + t] = (_Float16)0.f;
        }
    }

    {
        const float* Ws[4] = {W0, W1, W2, W3};
#pragma unroll
        for (int m = 0; m < 4; ++m) {
            const float* W = Ws[m];
            for (int idx = tid; idx < 64 * HD; idx += 256) {
                const int k = idx / HD;
                const int jj = idx - k * HD;
                B_lds[m * HD + jj][k] = (_Float16)W[idx];
            }
        }
    }

    __syncthreads();

    const int w = tid >> 6;
    const int lane = tid & 63;
    const int lr = lane & 15;
    const int lk = (lane >> 4) * 8;

    half8 a[4][2];
#pragma unroll
    for (int mt = 0; mt < 4; ++mt)
#pragma unroll
        for (int ks = 0; ks < 2; ++ks)
            a[mt][ks] = *reinterpret_cast<const half8*>(&A_lds[mt * 16 + lr][ks * 32 + lk]);

    half8 b[NTW][2];
#pragma unroll
    for (int nt = 0; nt < NTW; ++nt)
#pragma unroll
        for (int ks = 0; ks < 2; ++ks)
            b[nt][ks] = *reinterpret_cast<const half8*>(&B_lds[w * HD + nt * 16 + lr][ks * 32 + lk]);

    floatx4 acc[4][NTW];
#pragma unroll
    for (int mt = 0; mt < 4; ++mt)
#pragma unroll
        for (int nt = 0; nt < NTW; ++nt)
            acc[mt][nt] = (floatx4){0.f, 0.f, 0.f, 0.f};

#pragma unroll
    for (int mt = 0; mt < 4; ++mt)
#pragma unroll
        for (int nt = 0; nt < NTW; ++nt) {
            acc[mt][nt] = __builtin_amdgcn_mfma_f32_16x16x32_f16(a[mt][0], b[nt][0], acc[mt][nt], 0, 0, 0);
            acc[mt][nt] = __builtin_amdgcn_mfma_f32_16x16x32_f16(a[mt][1], b[nt][1], acc[mt][nt], 0, 0, 0);
        }

    const float* Bv = (w == 0) ? B0 : (w == 1) ? B1 : (w == 2) ? B2 : B3;
    float bias[NTW];
#pragma unroll
    for (int nt = 0; nt < NTW; ++nt) bias[nt] = Bv[nt * 16 + lr];

#pragma unroll
    for (int mt = 0; mt < 4; ++mt) {
#pragma unroll
        for (int nt = 0; nt < NTW; ++nt) {
            const int jj = nt * 16 + lr;
#pragma unroll
            for (int r = 0; r < 4; ++r) {
                const int node = n0 + mt * 16 + (lane >> 4) * 4 + r;
                if (node < n) {
                    const float val = acc[mt][nt][r] + bias[nt];
                    if (w == 0)      Q[(size_t)node * HD + jj] = val * qscale;
                    else if (w == 3) S[(size_t)node * HD + jj] = val;
                    else             KV[(size_t)node * 2 * HD + 2 * jj + (w - 1)] = __float2half(val);
                }
            }
        }
    }
}

// ---------------------------------------------------------------------------
// Adjacency build: atomic-free two-level counting sort by dst.
// Coarse bin = dst >> 8 (256 nodes per bin). No global atomics anywhere.
// ---------------------------------------------------------------------------

__global__ __launch_bounds__(256) void hist_coarse(
    const int* __restrict__ dst, int* __restrict__ hist,
    int e, int nbins, int nblk)
{
    __shared__ int lh[256];
    const int b = blockIdx.x;
    const int tid = threadIdx.x;
    if (tid < nbins) lh[tid] = 0;
    __syncthreads();

    const int base = b * CHUNK;
    const int end = min(base + CHUNK, e);
    for (int i = base + tid * 4; i < end; i += 1024) {
        if (i + 4 <= end) {
            const int4 d4 = *reinterpret_cast<const int4*>(dst + i);
            atomicAdd(&lh[d4.x >> 8], 1);
            atomicAdd(&lh[d4.y >> 8], 1);
            atomicAdd(&lh[d4.z >> 8], 1);
            atomicAdd(&lh[d4.w >> 8], 1);
        } else {
            for (int jj = i; jj < end; ++jj) atomicAdd(&lh[dst[jj] >> 8], 1);
        }
    }
    __syncthreads();
    if (tid < nbins) hist[tid * nblk + b] = lh[tid];
}

// single-block exclusive scan over the flat hist (m ~ 38416)
__global__ __launch_bounds__(1024) void scan_fused(
    const int* __restrict__ in, int* __restrict__ outp, int m)
{
    __shared__ int part[1024];
    const int t = threadIdx.x;
    const int per = (m + 1023) >> 10;
    const int lo = t * per;
    const int hi = min(lo + per, m);
    int s = 0;
    for (int i = lo; i < hi; ++i) s += in[i];
    part[t] = s;
    __syncthreads();
    for (int off = 1; off < 1024; off <<= 1) {
        int x = (t >= off) ? part[t - off] : 0;
        __syncthreads();
        part[t] += x;
        __syncthreads();
    }
    int run = part[t] - s;   // exclusive base of this thread's range
    for (int i = lo; i < hi; ++i) { const int v = in[i]; outp[i] = run; run += v; }
}

// replay chunks; ranks via LDS cursors; write (dst,src) grouped by coarse bin
__global__ __launch_bounds__(256) void scatter_coarse(
    const int* __restrict__ src, const int* __restrict__ dst,
    const int* __restrict__ hscan, int2* __restrict__ pairs,
    int e, int nbins, int nblk)
{
    __shared__ int cur[256];
    const int b = blockIdx.x;
    const int tid = threadIdx.x;
    if (tid < nbins) cur[tid] = hscan[tid * nblk + b];
    __syncthreads();

    const int base = b * CHUNK;
    const int end = min(base + CHUNK, e);
    for (int i = base + tid * 4; i < end; i += 1024) {
        if (i + 4 <= end) {
            const int4 d4 = *reinterpret_cast<const int4*>(dst + i);
            const int4 s4 = *reinterpret_cast<const int4*>(src + i);
            int p;
            p = atomicAdd(&cur[d4.x >> 8], 1); pairs[p] = make_int2(d4.x, s4.x);
            p = atomicAdd(&cur[d4.y >> 8], 1); pairs[p] = make_int2(d4.y, s4.y);
            p = atomicAdd(&cur[d4.z >> 8], 1); pairs[p] = make_int2(d4.z, s4.z);
            p = atomicAdd(&cur[d4.w >> 8], 1); pairs[p] = make_int2(d4.w, s4.w);
        } else {
            for (int jj = i; jj < end; ++jj) {
                const int d = dst[jj];
                const int p = atomicAdd(&cur[d >> 8], 1);
                pairs[p] = make_int2(d, src[jj]);
            }
        }
    }
}

// one block per coarse bin; LDS cursors over 256 local nodes
__global__ __launch_bounds__(512) void fine_bucket(
    const int2* __restrict__ pairs, const int* __restrict__ hscan,
    int* __restrict__ cnt, int* __restrict__ bucket,
    int e, int n, int nbins, int nblk)
{
    __shared__ int cur[256];
    const int g = blockIdx.x;
    const int tid = threadIdx.x;
    const int n0 = g << 8;
    if (tid < 256) cur[tid] = 0;
    __syncthreads();

    const int e0 = hscan[g * nblk];
    const int e1 = (g + 1 < nbins) ? hscan[(g + 1) * nblk] : e;
    for (int i = e0 + tid; i < e1; i += 512) {
        const int2 p = pairs[i];
        const int ld = p.x - n0;
        const int slot = atomicAdd(&cur[ld], 1);
        if (slot < BCAP) bucket[(size_t)(n0 + ld) * BCAP + slot] = p.y;
    }
    __syncthreads();
    const int node = n0 + tid;
    if (tid < 256 && node < n) cnt[node] = cur[tid];
}

// ---------------------------------------------------------------------------
// Attention layer 1: heads=2, d=32. One wave per node, 4 edges/iter,
// 4-deep software pipeline (up to 16 KV gathers in flight per wave).
// slot = lane>>4 (edge slot), j = lane&15. int4 gather = 4 ch (k,v) pairs.
// ---------------------------------------------------------------------------
__global__ void attn_h2(const float4* __restrict__ Qf4, const float4* __restrict__ Sf4,
                        const int4* __restrict__ KVi, const int* __restrict__ cnt,
                        const int* __restrict__ bucket, float4* __restrict__ houtf4, int n)
{
    const int wid = (blockIdx.x * blockDim.x + threadIdx.x) >> 6;
    if (wid >= n) return;
    const int lane = threadIdx.x & 63;
    const int slot = lane >> 4;
    const int j = lane & 15;

    const float4 q4 = Qf4[(size_t)wid * 16 + j];
    const int deg = min(cnt[wid], BCAP);
    const int* blist = bucket + (size_t)wid * BCAP;

    float acc0 = 0.f, acc1 = 0.f, acc2 = 0.f, acc3 = 0.f, den = 0.f;

    if (deg > 0) {
        const int nit = (deg + 3) >> 2;

#define ISSUE2(ITV, PV, VV)                                          \
        {   const int en_ = ((ITV) << 2) + slot;                     \
            VV = en_ < deg;                                          \
            const int sn_ = VV ? blist[en_] : 0;                     \
            PV = KVi[(size_t)sn_ * 16 + j]; }

#define CONSUME2(PV, VV)                                             \
        {   const float2 c0 = h2f(PV.x), c1 = h2f(PV.y),             \
                         c2 = h2f(PV.z), c3 = h2f(PV.w);             \
            float p = q4.x * c0.x;                                   \
            p = fmaf(q4.y, c1.x, p);                                 \
            p = fmaf(q4.z, c2.x, p);                                 \
            p = fmaf(q4.w, c3.x, p);                                 \
            p += __shfl_xor(p, 1);                                   \
            p += __shfl_xor(p, 2);                                   \
            p += __shfl_xor(p, 4);                                   \
            const float ex = VV ? __expf(p) : 0.f;                   \
            den += ex;                                               \
            acc0 = fmaf(ex, c0.y, acc0);                             \
            acc1 = fmaf(ex, c1.y, acc1);                             \
            acc2 = fmaf(ex, c2.y, acc2);                             \
            acc3 = fmaf(ex, c3.y, acc3); }

        int4 p0, p1, p2, p3;
        bool v0, v1, v2, v3;
        ISSUE2(0, p0, v0); ISSUE2(1, p1, v1); ISSUE2(2, p2, v2); ISSUE2(3, p3, v3);
        int it = 0;
        for (; it + 4 < nit; it += 4) {
            CONSUME2(p0, v0); ISSUE2(it + 4, p0, v0);
            CONSUME2(p1, v1); ISSUE2(it + 5, p1, v1);
            CONSUME2(p2, v2); ISSUE2(it + 6, p2, v2);
            CONSUME2(p3, v3); ISSUE2(it + 7, p3, v3);
        }
        CONSUME2(p0, v0); CONSUME2(p1, v1); CONSUME2(p2, v2); CONSUME2(p3, v3);
#undef ISSUE2
#undef CONSUME2
    }

    acc0 += __shfl_xor(acc0, 16); acc0 += __shfl_xor(acc0, 32);
    acc1 += __shfl_xor(acc1, 16); acc1 += __shfl_xor(acc1, 32);
    acc2 += __shfl_xor(acc2, 16); acc2 += __shfl_xor(acc2, 32);
    acc3 += __shfl_xor(acc3, 16); acc3 += __shfl_xor(acc3, 32);
    den  += __shfl_xor(den, 16);  den  += __shfl_xor(den, 32);

    const float inv = (den > 0.f) ? (1.f / den) : 0.f;
    const float4 s4 = Sf4[(size_t)wid * 16 + j];
    float4 o;
    o.x = fmaxf(fmaf(acc0, inv, s4.x), 0.f);
    o.y = fmaxf(fmaf(acc1, inv, s4.y), 0.f);
    o.z = fmaxf(fmaf(acc2, inv, s4.z), 0.f);
    o.w = fmaxf(fmaf(acc3, inv, s4.w), 0.f);
    if (lane < 16) houtf4[(size_t)wid * 16 + j] = o;
}

// ---------------------------------------------------------------------------
// Attention layer 2: heads=1, d=32. One wave per node, 8 edges/iter,
// 4-deep software pipeline (up to 32 KV gathers in flight per wave).
// ---------------------------------------------------------------------------
__global__ void attn_h1(const float4* __restrict__ Qf4, const float4* __restrict__ Sf4,
                        const int4* __restrict__ KVi, const int* __restrict__ cnt,
                        const int* __restrict__ bucket, float4* __restrict__ outf4, int n)
{
    const int wid = (blockIdx.x * blockDim.x + threadIdx.x) >> 6;
    if (wid >= n) return;
    const int lane = threadIdx.x & 63;
    const int slot = lane >> 3;
    const int j = lane & 7;

    const float4 q4 = Qf4[(size_t)wid * 8 + j];
    const int deg = min(cnt[wid], BCAP);
    const int* blist = bucket + (size_t)wid * BCAP;

    float acc0 = 0.f, acc1 = 0.f, acc2 = 0.f, acc3 = 0.f, den = 0.f;

    if (deg > 0) {
        const int nit = (deg + 7) >> 3;

#define ISSUE1(ITV, PV, VV)                                          \
        {   const int en_ = ((ITV) << 3) + slot;                     \
            VV = en_ < deg;                                          \
            const int sn_ = VV ? blist[en_] : 0;                     \
            PV = KVi[(size_t)sn_ * 8 + j]; }

#define CONSUME1(PV, VV)                                             \
        {   const float2 c0 = h2f(PV.x), c1 = h2f(PV.y),             \
                         c2 = h2f(PV.z), c3 = h2f(PV.w);             \
            float p = q4.x * c0.x;                                   \
            p = fmaf(q4.y, c1.x, p);                                 \
            p = fmaf(q4.z, c2.x, p);                                 \
            p = fmaf(q4.w, c3.x, p);                                 \
            p += __shfl_xor(p, 1);                                   \
            p += __shfl_xor(p, 2);                                   \
            p += __shfl_xor(p, 4);                                   \
            const float ex = VV ? __expf(p) : 0.f;                   \
            den += ex;                                               \
            acc0 = fmaf(ex, c0.y, acc0);                             \
            acc1 = fmaf(ex, c1.y, acc1);                             \
            acc2 = fmaf(ex, c2.y, acc2);                             \
            acc3 = fmaf(ex, c3.y, acc3); }

        int4 p0, p1, p2, p3;
        bool v0, v1, v2, v3;
        ISSUE1(0, p0, v0); ISSUE1(1, p1, v1); ISSUE1(2, p2, v2); ISSUE1(3, p3, v3);
        int it = 0;
        for (; it + 4 < nit; it += 4) {
            CONSUME1(p0, v0); ISSUE1(it + 4, p0, v0);
            CONSUME1(p1, v1); ISSUE1(it + 5, p1, v1);
            CONSUME1(p2, v2); ISSUE1(it + 6, p2, v2);
            CONSUME1(p3, v3); ISSUE1(it + 7, p3, v3);
        }
        CONSUME1(p0, v0); CONSUME1(p1, v1); CONSUME1(p2, v2); CONSUME1(p3, v3);
#undef ISSUE1
#undef CONSUME1
    }

    acc0 += __shfl_xor(acc0, 8); acc0 += __shfl_xor(acc0, 16); acc0 += __shfl_xor(acc0, 32);
    acc1 += __shfl_xor(acc1, 8); acc1 += __shfl_xor(acc1, 16); acc1 += __shfl_xor(acc1, 32);
    acc2 += __shfl_xor(acc2, 8); acc2 += __shfl_xor(acc2, 16); acc2 += __shfl_xor(acc2, 32);
    acc3 += __shfl_xor(acc3, 8); acc3 += __shfl_xor(acc3, 16); acc3 += __shfl_xor(acc3, 32);
    den  += __shfl_xor(den, 8);  den  += __shfl_xor(den, 16);  den  += __shfl_xor(den, 32);

    const float inv = (den > 0.f) ? (1.f / den) : 0.f;
    const float4 s4 = Sf4[(size_t)wid * 8 + j];
    float4 o;
    o.x = fmaf(acc0, inv, s4.x);
    o.y = fmaf(acc1, inv, s4.y);
    o.z = fmaf(acc2, inv, s4.z);
    o.w = fmaf(acc3, inv, s4.w);
    if (lane < 8) outf4[(size_t)wid * 8 + j] = o;
}

// ---------------------------------------------------------------------------
extern "C" void kernel_launch(void* const* d_in, const int* in_sizes, int n_in,
                              void* d_out, int out_size, void* d_ws, size_t ws_size,
                              hipStream_t stream)
{
    const float* x   = (const float*)d_in[0];
    const int* ei    = (const int*)d_in[1];
    const float* Wq1 = (const float*)d_in[2];  const float* bq1 = (const float*)d_in[3];
    const float* Wk1 = (const float*)d_in[4];  const float* bk1 = (const float*)d_in[5];
    const float* Wv1 = (const float*)d_in[6];  const float* bv1 = (const float*)d_in[7];
    const float* Ws1 = (const float*)d_in[8];  const float* bs1 = (const float*)d_in[9];
    const float* Wq2 = (const float*)d_in[10]; const float* bq2 = (const float*)d_in[11];
    const float* Wk2 = (const float*)d_in[12]; const float* bk2 = (const float*)d_in[13];
    const float* Wv2 = (const float*)d_in[14]; const float* bv2 = (const float*)d_in[15];
    const float* Ws2 = (const float*)d_in[16]; const float* bs2 = (const float*)d_in[17];

    const int n = in_sizes[0] / 64;   // 50000
    const int e = in_sizes[1] / 2;    // 800000
    const int* src = ei;
    const int* dst = ei + e;

    // workspace layout (layer2 q/s/kv alias layer1's)
    float*  q1  = (float*)d_ws;                        // n*64 f32
    float*  s1  = q1 + (size_t)n * 64;                 // n*64 f32
    __half* kv1 = (__half*)(s1 + (size_t)n * 64);      // n*128 fp16
    float*  h   = (float*)(kv1 + (size_t)n * 128);     // n*64 f32
    int*  cnt    = (int*)(h + (size_t)n * 64);         // n
    int*  bucket = cnt + n;                            // n*BCAP
    int2* pairs  = (int2*)(bucket + (size_t)n * BCAP); // e int2
    int*  hist   = (int*)(pairs + e);                  // nbins*nblk
    const int nbins = (n + 255) >> 8;                  // 196
    const int nblk  = (e + CHUNK - 1) / CHUNK;         // 196
    const int hsize = nbins * nblk;                    // 38416
    int*  hscan  = hist + hsize;                       // nbins*nblk

    float* out = (float*)d_out;
    const int nb_gemm = (n + 63) / 64;

    // ---- adjacency build: atomic-free counting sort (4 kernels) ----
    hist_coarse<<<nblk, 256, 0, stream>>>(dst, hist, e, nbins, nblk);
    scan_fused<<<1, 1024, 0, stream>>>(hist, hscan, hsize);
    scatter_coarse<<<nblk, 256, 0, stream>>>(src, dst, hscan, pairs, e, nbins, nblk);
    fine_bucket<<<nbins, 512, 0, stream>>>(pairs, hscan, cnt, bucket, e, n, nbins, nblk);

    // ---- layer 1 ----
    gemm_mfma<64><<<nb_gemm, 256, 0, stream>>>(
        x, n, Wq1, Wk1, Wv1, Ws1, bq1, bk1, bv1, bs1, q1, s1, kv1);
    attn_h2<<<(n + 3) / 4, 256, 0, stream>>>(
        (const float4*)q1, (const float4*)s1, (const int4*)kv1, cnt, bucket,
        (float4*)h, n);

    // ---- layer 2 (aliases layer-1 buffers) ----
    gemm_mfma<32><<<nb_gemm, 256, 0, stream>>>(
        h, n, Wq2, Wk2, Wv2, Ws2, bq2, bk2, bv2, bs2, q1, s1, kv1);
    attn_h1<<<(n + 3) / 4, 256, 0, stream>>>(
        (const float4*)q1, (const float4*)s1, (const int4*)kv1, cnt, bucket,
        (float4*)out, n);
}

// Round 9
// 136.428 us; speedup vs baseline: 1.3296x; 1.3296x over previous
//
#include <hip/hip_runtime.h>
#include <hip/hip_bf16.h>
#include <hip/hip_fp16.h>

#define CHUNK 4096       // edges per histogram/scatter block
#define BCAP 64          // bucket capacity per node (deg ~ Poisson(16))
#define SCAN_BS 1024

typedef _Float16 half8 __attribute__((ext_vector_type(8)));
typedef float floatx4 __attribute__((ext_vector_type(4)));

__device__ __forceinline__ float2 h2f(int u)
{
    __half2 h = *reinterpret_cast<__half2*>(&u);
    return __half22float2(h);
}

// ---------------------------------------------------------------------------
// MFMA fused GEMM: [Q|K|V|S] = X[n][64] @ W(64 x 4*HD) + b, per 64-node tile.
// Block = 256 thr / 4 waves; wave w owns matrix w (q,k,v,s). K=64, two k-steps.
//   q -> Q (f32, pre-scaled by 1/sqrt(32)); s -> S (f32)
//   k,v -> KV interleaved fp16: KV[node*2*HD + 2*jj + {0,1}]
// ---------------------------------------------------------------------------
template <int HD>   // 64 (layer1) or 32 (layer2)
__global__ __launch_bounds__(256) void gemm_mfma(
    const float* __restrict__ X, int n,
    const float* __restrict__ W0, const float* __restrict__ W1,
    const float* __restrict__ W2, const float* __restrict__ W3,
    const float* __restrict__ B0, const float* __restrict__ B1,
    const float* __restrict__ B2, const float* __restrict__ B3,
    float* __restrict__ Q, float* __restrict__ S, __half* __restrict__ KV)
{
    constexpr int NTW = HD / 16;
    const float qscale = 0.17677669529663687f;  // 1/sqrt(32)

    __shared__ _Float16 A_lds[64][72];
    __shared__ _Float16 B_lds[4 * HD][72];

    const int tid = threadIdx.x;
    const int n0 = blockIdx.x * 64;

    {
        const int row = tid >> 2;
        const int cb  = (tid & 3) * 16;
        const int gnode = n0 + row;
        if (gnode < n) {
            const float4* xg = reinterpret_cast<const float4*>(X + (size_t)gnode * 64 + cb);
#pragma unroll
            for (int t = 0; t < 4; ++t) {
                const float4 v = xg[t];
                A_lds[row][cb + 4 * t + 0] = (_Float16)v.x;
                A_lds[row][cb + 4 * t + 1] = (_Float16)v.y;
                A_lds[row][cb + 4 * t + 2] = (_Float16)v.z;
                A_lds[row][cb + 4 * t + 3] = (_Float16)v.w;
            }
        } else {
#pragma unroll
            for (int t = 0; t < 16; ++t) A_lds[row][cb + t] = (_Float16)0.f;
        }
    }

    {
        const float* Ws[4] = {W0, W1, W2, W3};
#pragma unroll
        for (int m = 0; m < 4; ++m) {
            const float* W = Ws[m];
            for (int idx = tid; idx < 64 * HD; idx += 256) {
                const int k = idx / HD;
                const int jj = idx - k * HD;
                B_lds[m * HD + jj][k] = (_Float16)W[idx];
            }
        }
    }

    __syncthreads();

    const int w = tid >> 6;
    const int lane = tid & 63;
    const int lr = lane & 15;
    const int lk = (lane >> 4) * 8;

    half8 a[4][2];
#pragma unroll
    for (int mt = 0; mt < 4; ++mt)
#pragma unroll
        for (int ks = 0; ks < 2; ++ks)
            a[mt][ks] = *reinterpret_cast<const half8*>(&A_lds[mt * 16 + lr][ks * 32 + lk]);

    half8 b[NTW][2];
#pragma unroll
    for (int nt = 0; nt < NTW; ++nt)
#pragma unroll
        for (int ks = 0; ks < 2; ++ks)
            b[nt][ks] = *reinterpret_cast<const half8*>(&B_lds[w * HD + nt * 16 + lr][ks * 32 + lk]);

    floatx4 acc[4][NTW];
#pragma unroll
    for (int mt = 0; mt < 4; ++mt)
#pragma unroll
        for (int nt = 0; nt < NTW; ++nt)
            acc[mt][nt] = (floatx4){0.f, 0.f, 0.f, 0.f};

#pragma unroll
    for (int mt = 0; mt < 4; ++mt)
#pragma unroll
        for (int nt = 0; nt < NTW; ++nt) {
            acc[mt][nt] = __builtin_amdgcn_mfma_f32_16x16x32_f16(a[mt][0], b[nt][0], acc[mt][nt], 0, 0, 0);
            acc[mt][nt] = __builtin_amdgcn_mfma_f32_16x16x32_f16(a[mt][1], b[nt][1], acc[mt][nt], 0, 0, 0);
        }

    const float* Bv = (w == 0) ? B0 : (w == 1) ? B1 : (w == 2) ? B2 : B3;
    float bias[NTW];
#pragma unroll
    for (int nt = 0; nt < NTW; ++nt) bias[nt] = Bv[nt * 16 + lr];

#pragma unroll
    for (int mt = 0; mt < 4; ++mt) {
#pragma unroll
        for (int nt = 0; nt < NTW; ++nt) {
            const int jj = nt * 16 + lr;
#pragma unroll
            for (int r = 0; r < 4; ++r) {
                const int node = n0 + mt * 16 + (lane >> 4) * 4 + r;
                if (node < n) {
                    const float val = acc[mt][nt][r] + bias[nt];
                    if (w == 0)      Q[(size_t)node * HD + jj] = val * qscale;
                    else if (w == 3) S[(size_t)node * HD + jj] = val;
                    else             KV[(size_t)node * 2 * HD + 2 * jj + (w - 1)] = __float2half(val);
                }
            }
        }
    }
}

// ---------------------------------------------------------------------------
// Adjacency build: atomic-free two-level counting sort by dst.
// Coarse bin = dst >> 8 (256 nodes per bin). No global atomics anywhere.
// ---------------------------------------------------------------------------

__global__ __launch_bounds__(256) void hist_coarse(
    const int* __restrict__ dst, int* __restrict__ hist,
    int e, int nbins, int nblk)
{
    __shared__ int lh[256];
    const int b = blockIdx.x;
    const int tid = threadIdx.x;
    if (tid < nbins) lh[tid] = 0;
    __syncthreads();

    const int base = b * CHUNK;
    const int end = min(base + CHUNK, e);
    for (int i = base + tid * 4; i < end; i += 1024) {
        if (i + 4 <= end) {
            const int4 d4 = *reinterpret_cast<const int4*>(dst + i);
            atomicAdd(&lh[d4.x >> 8], 1);
            atomicAdd(&lh[d4.y >> 8], 1);
            atomicAdd(&lh[d4.z >> 8], 1);
            atomicAdd(&lh[d4.w >> 8], 1);
        } else {
            for (int jj = i; jj < end; ++jj) atomicAdd(&lh[dst[jj] >> 8], 1);
        }
    }
    __syncthreads();
    if (tid < nbins) hist[tid * nblk + b] = lh[tid];
}

// multi-block exclusive scan (3 kernels) over the flat hist
__global__ void scan1(const int* __restrict__ in, int* __restrict__ outp,
                      int* __restrict__ bsum, int m)
{
    __shared__ int lds[SCAN_BS];
    const int t = threadIdx.x;
    const int i = blockIdx.x * SCAN_BS + t;
    const int v = (i < m) ? in[i] : 0;
    lds[t] = v;
    __syncthreads();
    for (int off = 1; off < SCAN_BS; off <<= 1) {
        int x = (t >= off) ? lds[t - off] : 0;
        __syncthreads();
        lds[t] += x;
        __syncthreads();
    }
    if (i < m) outp[i] = lds[t] - v;  // exclusive
    if (t == SCAN_BS - 1) bsum[blockIdx.x] = lds[t];
}

__global__ void scan2(int* __restrict__ bsum, int nb)
{
    if (threadIdx.x == 0 && blockIdx.x == 0) {
        int run = 0;
        for (int b = 0; b < nb; ++b) { int v = bsum[b]; bsum[b] = run; run += v; }
    }
}

__global__ void scan3b(int* __restrict__ outp, const int* __restrict__ bsum, int m)
{
    int i = blockIdx.x * blockDim.x + threadIdx.x;
    if (i < m) outp[i] += bsum[i / SCAN_BS];
}

// replay chunks; ranks via LDS cursors; write (dst,src) grouped by coarse bin
__global__ __launch_bounds__(256) void scatter_coarse(
    const int* __restrict__ src, const int* __restrict__ dst,
    const int* __restrict__ hscan, int2* __restrict__ pairs,
    int e, int nbins, int nblk)
{
    __shared__ int cur[256];
    const int b = blockIdx.x;
    const int tid = threadIdx.x;
    if (tid < nbins) cur[tid] = hscan[tid * nblk + b];
    __syncthreads();

    const int base = b * CHUNK;
    const int end = min(base + CHUNK, e);
    for (int i = base + tid * 4; i < end; i += 1024) {
        if (i + 4 <= end) {
            const int4 d4 = *reinterpret_cast<const int4*>(dst + i);
            const int4 s4 = *reinterpret_cast<const int4*>(src + i);
            int p;
            p = atomicAdd(&cur[d4.x >> 8], 1); pairs[p] = make_int2(d4.x, s4.x);
            p = atomicAdd(&cur[d4.y >> 8], 1); pairs[p] = make_int2(d4.y, s4.y);
            p = atomicAdd(&cur[d4.z >> 8], 1); pairs[p] = make_int2(d4.z, s4.z);
            p = atomicAdd(&cur[d4.w >> 8], 1); pairs[p] = make_int2(d4.w, s4.w);
        } else {
            for (int jj = i; jj < end; ++jj) {
                const int d = dst[jj];
                const int p = atomicAdd(&cur[d >> 8], 1);
                pairs[p] = make_int2(d, src[jj]);
            }
        }
    }
}

// one block per coarse bin; LDS cursors over 256 local nodes
__global__ __launch_bounds__(512) void fine_bucket(
    const int2* __restrict__ pairs, const int* __restrict__ hscan,
    int* __restrict__ cnt, int* __restrict__ bucket,
    int e, int n, int nbins, int nblk)
{
    __shared__ int cur[256];
    const int g = blockIdx.x;
    const int tid = threadIdx.x;
    const int n0 = g << 8;
    if (tid < 256) cur[tid] = 0;
    __syncthreads();

    const int e0 = hscan[g * nblk];
    const int e1 = (g + 1 < nbins) ? hscan[(g + 1) * nblk] : e;
    for (int i = e0 + tid; i < e1; i += 512) {
        const int2 p = pairs[i];
        const int ld = p.x - n0;
        const int slot = atomicAdd(&cur[ld], 1);
        if (slot < BCAP) bucket[(size_t)(n0 + ld) * BCAP + slot] = p.y;
    }
    __syncthreads();
    const int node = n0 + tid;
    if (tid < 256 && node < n) cnt[node] = cur[tid];
}

// ---------------------------------------------------------------------------
// Attention layer 1: heads=2, d=32. One wave per node, 4 edges/iter,
// 4-deep software pipeline (up to 16 KV gathers in flight per wave).
// slot = lane>>4 (edge slot), j = lane&15. int4 gather = 4 ch (k,v) pairs.
// ---------------------------------------------------------------------------
__global__ void attn_h2(const float4* __restrict__ Qf4, const float4* __restrict__ Sf4,
                        const int4* __restrict__ KVi, const int* __restrict__ cnt,
                        const int* __restrict__ bucket, float4* __restrict__ houtf4, int n)
{
    const int wid = (blockIdx.x * blockDim.x + threadIdx.x) >> 6;
    if (wid >= n) return;
    const int lane = threadIdx.x & 63;
    const int slot = lane >> 4;
    const int j = lane & 15;

    const float4 q4 = Qf4[(size_t)wid * 16 + j];
    const int deg = min(cnt[wid], BCAP);
    const int* blist = bucket + (size_t)wid * BCAP;

    float acc0 = 0.f, acc1 = 0.f, acc2 = 0.f, acc3 = 0.f, den = 0.f;

    if (deg > 0) {
        const int nit = (deg + 3) >> 2;

#define ISSUE2(ITV, PV, VV)                                          \
        {   const int en_ = ((ITV) << 2) + slot;                     \
            VV = en_ < deg;                                          \
            const int sn_ = VV ? blist[en_] : 0;                     \
            PV = KVi[(size_t)sn_ * 16 + j]; }

#define CONSUME2(PV, VV)                                             \
        {   const float2 c0 = h2f(PV.x), c1 = h2f(PV.y),             \
                         c2 = h2f(PV.z), c3 = h2f(PV.w);             \
            float p = q4.x * c0.x;                                   \
            p = fmaf(q4.y, c1.x, p);                                 \
            p = fmaf(q4.z, c2.x, p);                                 \
            p = fmaf(q4.w, c3.x, p);                                 \
            p += __shfl_xor(p, 1);                                   \
            p += __shfl_xor(p, 2);                                   \
            p += __shfl_xor(p, 4);                                   \
            const float ex = VV ? __expf(p) : 0.f;                   \
            den += ex;                                               \
            acc0 = fmaf(ex, c0.y, acc0);                             \
            acc1 = fmaf(ex, c1.y, acc1);                             \
            acc2 = fmaf(ex, c2.y, acc2);                             \
            acc3 = fmaf(ex, c3.y, acc3); }

        int4 p0, p1, p2, p3;
        bool v0, v1, v2, v3;
        ISSUE2(0, p0, v0); ISSUE2(1, p1, v1); ISSUE2(2, p2, v2); ISSUE2(3, p3, v3);
        int it = 0;
        for (; it + 4 < nit; it += 4) {
            CONSUME2(p0, v0); ISSUE2(it + 4, p0, v0);
            CONSUME2(p1, v1); ISSUE2(it + 5, p1, v1);
            CONSUME2(p2, v2); ISSUE2(it + 6, p2, v2);
            CONSUME2(p3, v3); ISSUE2(it + 7, p3, v3);
        }
        CONSUME2(p0, v0); CONSUME2(p1, v1); CONSUME2(p2, v2); CONSUME2(p3, v3);
#undef ISSUE2
#undef CONSUME2
    }

    acc0 += __shfl_xor(acc0, 16); acc0 += __shfl_xor(acc0, 32);
    acc1 += __shfl_xor(acc1, 16); acc1 += __shfl_xor(acc1, 32);
    acc2 += __shfl_xor(acc2, 16); acc2 += __shfl_xor(acc2, 32);
    acc3 += __shfl_xor(acc3, 16); acc3 += __shfl_xor(acc3, 32);
    den  += __shfl_xor(den, 16);  den  += __shfl_xor(den, 32);

    const float inv = (den > 0.f) ? (1.f / den) : 0.f;
    const float4 s4 = Sf4[(size_t)wid * 16 + j];
    float4 o;
    o.x = fmaxf(fmaf(acc0, inv, s4.x), 0.f);
    o.y = fmaxf(fmaf(acc1, inv, s4.y), 0.f);
    o.z = fmaxf(fmaf(acc2, inv, s4.z), 0.f);
    o.w = fmaxf(fmaf(acc3, inv, s4.w), 0.f);
    if (lane < 16) houtf4[(size_t)wid * 16 + j] = o;
}

// ---------------------------------------------------------------------------
// Attention layer 2: heads=1, d=32. One wave per node, 8 edges/iter,
// 4-deep software pipeline (up to 32 KV gathers in flight per wave).
// ---------------------------------------------------------------------------
__global__ void attn_h1(const float4* __restrict__ Qf4, const float4* __restrict__ Sf4,
                        const int4* __restrict__ KVi, const int* __restrict__ cnt,
                        const int* __restrict__ bucket, float4* __restrict__ outf4, int n)
{
    const int wid = (blockIdx.x * blockDim.x + threadIdx.x) >> 6;
    if (wid >= n) return;
    const int lane = threadIdx.x & 63;
    const int slot = lane >> 3;
    const int j = lane & 7;

    const float4 q4 = Qf4[(size_t)wid * 8 + j];
    const int deg = min(cnt[wid], BCAP);
    const int* blist = bucket + (size_t)wid * BCAP;

    float acc0 = 0.f, acc1 = 0.f, acc2 = 0.f, acc3 = 0.f, den = 0.f;

    if (deg > 0) {
        const int nit = (deg + 7) >> 3;

#define ISSUE1(ITV, PV, VV)                                          \
        {   const int en_ = ((ITV) << 3) + slot;                     \
            VV = en_ < deg;                                          \
            const int sn_ = VV ? blist[en_] : 0;                     \
            PV = KVi[(size_t)sn_ * 8 + j]; }

#define CONSUME1(PV, VV)                                             \
        {   const float2 c0 = h2f(PV.x), c1 = h2f(PV.y),             \
                         c2 = h2f(PV.z), c3 = h2f(PV.w);             \
            float p = q4.x * c0.x;                                   \
            p = fmaf(q4.y, c1.x, p);                                 \
            p = fmaf(q4.z, c2.x, p);                                 \
            p = fmaf(q4.w, c3.x, p);                                 \
            p += __shfl_xor(p, 1);                                   \
            p += __shfl_xor(p, 2);                                   \
            p += __shfl_xor(p, 4);                                   \
            const float ex = VV ? __expf(p) : 0.f;                   \
            den += ex;                                               \
            acc0 = fmaf(ex, c0.y, acc0);                             \
            acc1 = fmaf(ex, c1.y, acc1);                             \
            acc2 = fmaf(ex, c2.y, acc2);                             \
            acc3 = fmaf(ex, c3.y, acc3); }

        int4 p0, p1, p2, p3;
        bool v0, v1, v2, v3;
        ISSUE1(0, p0, v0); ISSUE1(1, p1, v1); ISSUE1(2, p2, v2); ISSUE1(3, p3, v3);
        int it = 0;
        for (; it + 4 < nit; it += 4) {
            CONSUME1(p0, v0); ISSUE1(it + 4, p0, v0);
            CONSUME1(p1, v1); ISSUE1(it + 5, p1, v1);
            CONSUME1(p2, v2); ISSUE1(it + 6, p2, v2);
            CONSUME1(p3, v3); ISSUE1(it + 7, p3, v3);
        }
        CONSUME1(p0, v0); CONSUME1(p1, v1); CONSUME1(p2, v2); CONSUME1(p3, v3);
#undef ISSUE1
#undef CONSUME1
    }

    acc0 += __shfl_xor(acc0, 8); acc0 += __shfl_xor(acc0, 16); acc0 += __shfl_xor(acc0, 32);
    acc1 += __shfl_xor(acc1, 8); acc1 += __shfl_xor(acc1, 16); acc1 += __shfl_xor(acc1, 32);
    acc2 += __shfl_xor(acc2, 8); acc2 += __shfl_xor(acc2, 16); acc2 += __shfl_xor(acc2, 32);
    acc3 += __shfl_xor(acc3, 8); acc3 += __shfl_xor(acc3, 16); acc3 += __shfl_xor(acc3, 32);
    den  += __shfl_xor(den, 8);  den  += __shfl_xor(den, 16);  den  += __shfl_xor(den, 32);

    const float inv = (den > 0.f) ? (1.f / den) : 0.f;
    const float4 s4 = Sf4[(size_t)wid * 8 + j];
    float4 o;
    o.x = fmaf(acc0, inv, s4.x);
    o.y = fmaf(acc1, inv, s4.y);
    o.z = fmaf(acc2, inv, s4.z);
    o.w = fmaf(acc3, inv, s4.w);
    if (lane < 8) outf4[(size_t)wid * 8 + j] = o;
}

// ---------------------------------------------------------------------------
extern "C" void kernel_launch(void* const* d_in, const int* in_sizes, int n_in,
                              void* d_out, int out_size, void* d_ws, size_t ws_size,
                              hipStream_t stream)
{
    const float* x   = (const float*)d_in[0];
    const int* ei    = (const int*)d_in[1];
    const float* Wq1 = (const float*)d_in[2];  const float* bq1 = (const float*)d_in[3];
    const float* Wk1 = (const float*)d_in[4];  const float* bk1 = (const float*)d_in[5];
    const float* Wv1 = (const float*)d_in[6];  const float* bv1 = (const float*)d_in[7];
    const float* Ws1 = (const float*)d_in[8];  const float* bs1 = (const float*)d_in[9];
    const float* Wq2 = (const float*)d_in[10]; const float* bq2 = (const float*)d_in[11];
    const float* Wk2 = (const float*)d_in[12]; const float* bk2 = (const float*)d_in[13];
    const float* Wv2 = (const float*)d_in[14]; const float* bv2 = (const float*)d_in[15];
    const float* Ws2 = (const float*)d_in[16]; const float* bs2 = (const float*)d_in[17];

    const int n = in_sizes[0] / 64;   // 50000
    const int e = in_sizes[1] / 2;    // 800000
    const int* src = ei;
    const int* dst = ei + e;

    // workspace layout (layer2 q/s/kv alias layer1's)
    float*  q1  = (float*)d_ws;                        // n*64 f32
    float*  s1  = q1 + (size_t)n * 64;                 // n*64 f32
    __half* kv1 = (__half*)(s1 + (size_t)n * 64);      // n*128 fp16
    float*  h   = (float*)(kv1 + (size_t)n * 128);     // n*64 f32
    int*  cnt    = (int*)(h + (size_t)n * 64);         // n
    int*  bucket = cnt + n;                            // n*BCAP
    int2* pairs  = (int2*)(bucket + (size_t)n * BCAP); // e int2
    int*  hist   = (int*)(pairs + e);                  // nbins*nblk
    const int nbins = (n + 255) >> 8;                  // 196
    const int nblk  = (e + CHUNK - 1) / CHUNK;         // 196
    const int hsize = nbins * nblk;                    // 38416
    int*  hscan  = hist + hsize;                       // nbins*nblk
    int*  bsum   = hscan + hsize;                      // scan block sums (<=64)

    float* out = (float*)d_out;
    const int nb_scan = (hsize + SCAN_BS - 1) / SCAN_BS;
    const int nb_gemm = (n + 63) / 64;

    // ---- adjacency build: atomic-free counting sort ----
    hist_coarse<<<nblk, 256, 0, stream>>>(dst, hist, e, nbins, nblk);
    scan1<<<nb_scan, SCAN_BS, 0, stream>>>(hist, hscan, bsum, hsize);
    scan2<<<1, 64, 0, stream>>>(bsum, nb_scan);
    scan3b<<<(hsize + 255) / 256, 256, 0, stream>>>(hscan, bsum, hsize);
    scatter_coarse<<<nblk, 256, 0, stream>>>(src, dst, hscan, pairs, e, nbins, nblk);
    fine_bucket<<<nbins, 512, 0, stream>>>(pairs, hscan, cnt, bucket, e, n, nbins, nblk);

    // ---- layer 1 ----
    gemm_mfma<64><<<nb_gemm, 256, 0, stream>>>(
        x, n, Wq1, Wk1, Wv1, Ws1, bq1, bk1, bv1, bs1, q1, s1, kv1);
    attn_h2<<<(n + 3) / 4, 256, 0, stream>>>(
        (const float4*)q1, (const float4*)s1, (const int4*)kv1, cnt, bucket,
        (float4*)h, n);

    // ---- layer 2 (aliases layer-1 buffers) ----
    gemm_mfma<32><<<nb_gemm, 256, 0, stream>>>(
        h, n, Wq2, Wk2, Wv2, Ws2, bq2, bk2, bv2, bs2, q1, s1, kv1);
    attn_h1<<<(n + 3) / 4, 256, 0, stream>>>(
        (const float4*)q1, (const float4*)s1, (const int4*)kv1, cnt, bucket,
        (float4*)out, n);
}

// Round 10
// 126.028 us; speedup vs baseline: 1.4394x; 1.0825x over previous
//
#include <hip/hip_runtime.h>
#include <hip/hip_bf16.h>
#include <hip/hip_fp16.h>

#define CHUNK 4096       // edges per scatter block
#define BCAP 64          // bucket capacity per node (deg ~ Poisson(16))
#define BIN_CAP 6144     // pairs capacity per 256-node coarse bin (Poisson(4096), 32 sigma)

typedef _Float16 half8 __attribute__((ext_vector_type(8)));
typedef float floatx4 __attribute__((ext_vector_type(4)));

__device__ __forceinline__ float2 h2f(int u)
{
    __half2 h = *reinterpret_cast<__half2*>(&u);
    return __half22float2(h);
}

// ---------------------------------------------------------------------------
// MFMA fused GEMM: [Q|K|V|S] = X[n][64] @ W(64 x 4*HD) + b, per 64-node tile.
// Block = 256 thr / 4 waves; wave w owns matrix w (q,k,v,s). K=64, two k-steps.
//   q -> Q (f32, pre-scaled by 1/sqrt(32)); s -> S (f32)
//   k,v -> KV interleaved fp16: KV[node*2*HD + 2*jj + {0,1}]
// ---------------------------------------------------------------------------
template <int HD>   // 64 (layer1) or 32 (layer2)
__global__ __launch_bounds__(256) void gemm_mfma(
    const float* __restrict__ X, int n,
    const float* __restrict__ W0, const float* __restrict__ W1,
    const float* __restrict__ W2, const float* __restrict__ W3,
    const float* __restrict__ B0, const float* __restrict__ B1,
    const float* __restrict__ B2, const float* __restrict__ B3,
    float* __restrict__ Q, float* __restrict__ S, __half* __restrict__ KV)
{
    constexpr int NTW = HD / 16;
    const float qscale = 0.17677669529663687f;  // 1/sqrt(32)

    __shared__ _Float16 A_lds[64][72];
    __shared__ _Float16 B_lds[4 * HD][72];

    const int tid = threadIdx.x;
    const int n0 = blockIdx.x * 64;

    {
        const int row = tid >> 2;
        const int cb  = (tid & 3) * 16;
        const int gnode = n0 + row;
        if (gnode < n) {
            const float4* xg = reinterpret_cast<const float4*>(X + (size_t)gnode * 64 + cb);
#pragma unroll
            for (int t = 0; t < 4; ++t) {
                const float4 v = xg[t];
                A_lds[row][cb + 4 * t + 0] = (_Float16)v.x;
                A_lds[row][cb + 4 * t + 1] = (_Float16)v.y;
                A_lds[row][cb + 4 * t + 2] = (_Float16)v.z;
                A_lds[row][cb + 4 * t + 3] = (_Float16)v.w;
            }
        } else {
#pragma unroll
            for (int t = 0; t < 16; ++t) A_lds[row][cb + t] = (_Float16)0.f;
        }
    }

    {
        const float* Ws[4] = {W0, W1, W2, W3};
#pragma unroll
        for (int m = 0; m < 4; ++m) {
            const float* W = Ws[m];
            for (int idx = tid; idx < 64 * HD; idx += 256) {
                const int k = idx / HD;
                const int jj = idx - k * HD;
                B_lds[m * HD + jj][k] = (_Float16)W[idx];
            }
        }
    }

    __syncthreads();

    const int w = tid >> 6;
    const int lane = tid & 63;
    const int lr = lane & 15;
    const int lk = (lane >> 4) * 8;

    half8 a[4][2];
#pragma unroll
    for (int mt = 0; mt < 4; ++mt)
#pragma unroll
        for (int ks = 0; ks < 2; ++ks)
            a[mt][ks] = *reinterpret_cast<const half8*>(&A_lds[mt * 16 + lr][ks * 32 + lk]);

    half8 b[NTW][2];
#pragma unroll
    for (int nt = 0; nt < NTW; ++nt)
#pragma unroll
        for (int ks = 0; ks < 2; ++ks)
            b[nt][ks] = *reinterpret_cast<const half8*>(&B_lds[w * HD + nt * 16 + lr][ks * 32 + lk]);

    floatx4 acc[4][NTW];
#pragma unroll
    for (int mt = 0; mt < 4; ++mt)
#pragma unroll
        for (int nt = 0; nt < NTW; ++nt)
            acc[mt][nt] = (floatx4){0.f, 0.f, 0.f, 0.f};

#pragma unroll
    for (int mt = 0; mt < 4; ++mt)
#pragma unroll
        for (int nt = 0; nt < NTW; ++nt) {
            acc[mt][nt] = __builtin_amdgcn_mfma_f32_16x16x32_f16(a[mt][0], b[nt][0], acc[mt][nt], 0, 0, 0);
            acc[mt][nt] = __builtin_amdgcn_mfma_f32_16x16x32_f16(a[mt][1], b[nt][1], acc[mt][nt], 0, 0, 0);
        }

    const float* Bv = (w == 0) ? B0 : (w == 1) ? B1 : (w == 2) ? B2 : B3;
    float bias[NTW];
#pragma unroll
    for (int nt = 0; nt < NTW; ++nt) bias[nt] = Bv[nt * 16 + lr];

#pragma unroll
    for (int mt = 0; mt < 4; ++mt) {
#pragma unroll
        for (int nt = 0; nt < NTW; ++nt) {
            const int jj = nt * 16 + lr;
#pragma unroll
            for (int r = 0; r < 4; ++r) {
                const int node = n0 + mt * 16 + (lane >> 4) * 4 + r;
                if (node < n) {
                    const float val = acc[mt][nt][r] + bias[nt];
                    if (w == 0)      Q[(size_t)node * HD + jj] = val * qscale;
                    else if (w == 3) S[(size_t)node * HD + jj] = val;
                    else             KV[(size_t)node * 2 * HD + 2 * jj + (w - 1)] = __float2half(val);
                }
            }
        }
    }
}

// ---------------------------------------------------------------------------
// Adjacency build, 3 kernels:
//  1. init_bincur: bincur[g] = g*BIN_CAP (fixed-capacity coarse bins)
//  2. scatter_fused: per-chunk LDS histogram -> claim per-bin ranges with one
//     global atomic per (block,bin) -> write (dst,src) pairs grouped by bin
//  3. fine_bucket: per bin, LDS cursors over 256 nodes -> bucket + cnt
// ---------------------------------------------------------------------------
__global__ void init_bincur(int* __restrict__ bincur, int nbins)
{
    int i = blockIdx.x * blockDim.x + threadIdx.x;
    if (i < nbins) bincur[i] = i * BIN_CAP;
}

__global__ __launch_bounds__(256) void scatter_fused(
    const int* __restrict__ src, const int* __restrict__ dst,
    int* __restrict__ bincur, int2* __restrict__ pairs,
    int e, int nbins)
{
    __shared__ int lh[256];     // per-bin chunk counts, then per-bin local cursor
    __shared__ int lbase[256];  // claimed global base per bin
    const int b = blockIdx.x;
    const int tid = threadIdx.x;
    if (tid < 256) lh[tid] = 0;
    __syncthreads();

    const int base = b * CHUNK;
    const int end = min(base + CHUNK, e);

    // pass 1: LDS histogram of this chunk
    for (int i = base + tid * 4; i < end; i += 1024) {
        if (i + 4 <= end) {
            const int4 d4 = *reinterpret_cast<const int4*>(dst + i);
            atomicAdd(&lh[d4.x >> 8], 1);
            atomicAdd(&lh[d4.y >> 8], 1);
            atomicAdd(&lh[d4.z >> 8], 1);
            atomicAdd(&lh[d4.w >> 8], 1);
        } else {
            for (int jj = i; jj < end; ++jj) atomicAdd(&lh[dst[jj] >> 8], 1);
        }
    }
    __syncthreads();

    // claim contiguous range in each touched bin
    int mycnt = 0;
    if (tid < nbins) {
        mycnt = lh[tid];
        if (mycnt > 0) lbase[tid] = atomicAdd(&bincur[tid], mycnt);
    }
    __syncthreads();
    if (tid < 256) lh[tid] = 0;     // reuse as local cursor
    __syncthreads();

    // pass 2: replay, place pairs grouped by bin
    for (int i = base + tid * 4; i < end; i += 1024) {
        if (i + 4 <= end) {
            const int4 d4 = *reinterpret_cast<const int4*>(dst + i);
            const int4 s4 = *reinterpret_cast<const int4*>(src + i);
            int bin, off;
            bin = d4.x >> 8; off = atomicAdd(&lh[bin], 1); pairs[lbase[bin] + off] = make_int2(d4.x, s4.x);
            bin = d4.y >> 8; off = atomicAdd(&lh[bin], 1); pairs[lbase[bin] + off] = make_int2(d4.y, s4.y);
            bin = d4.z >> 8; off = atomicAdd(&lh[bin], 1); pairs[lbase[bin] + off] = make_int2(d4.z, s4.z);
            bin = d4.w >> 8; off = atomicAdd(&lh[bin], 1); pairs[lbase[bin] + off] = make_int2(d4.w, s4.w);
        } else {
            for (int jj = i; jj < end; ++jj) {
                const int d = dst[jj];
                const int bin = d >> 8;
                const int off = atomicAdd(&lh[bin], 1);
                pairs[lbase[bin] + off] = make_int2(d, src[jj]);
            }
        }
    }
}

__global__ __launch_bounds__(512) void fine_bucket(
    const int2* __restrict__ pairs, const int* __restrict__ bincur,
    int* __restrict__ cnt, int* __restrict__ bucket, int n)
{
    __shared__ int cur[256];
    const int g = blockIdx.x;
    const int tid = threadIdx.x;
    const int n0 = g << 8;
    if (tid < 256) cur[tid] = 0;
    __syncthreads();

    const int e0 = g * BIN_CAP;
    const int e1 = bincur[g];          // base + total count after scatter
    for (int i = e0 + tid; i < e1; i += 512) {
        const int2 p = pairs[i];
        const int slot = atomicAdd(&cur[p.x - n0], 1);
        if (slot < BCAP) bucket[(size_t)p.x * BCAP + slot] = p.y;
    }
    __syncthreads();
    const int node = n0 + tid;
    if (tid < 256 && node < n) cnt[node] = cur[tid];
}

// ---------------------------------------------------------------------------
// Attention layer 1: heads=2, d=32. One wave per node, 4 edges/iter,
// 2-deep pipeline (prefetch next iteration's 4 gathers).
// slot = lane>>4 (edge slot), j = lane&15. int4 gather = 4 ch (k,v) pairs.
// ---------------------------------------------------------------------------
__global__ void attn_h2(const float4* __restrict__ Qf4, const float4* __restrict__ Sf4,
                        const int4* __restrict__ KVi, const int* __restrict__ cnt,
                        const int* __restrict__ bucket, float4* __restrict__ houtf4, int n)
{
    const int wid = (blockIdx.x * blockDim.x + threadIdx.x) >> 6;
    if (wid >= n) return;
    const int lane = threadIdx.x & 63;
    const int slot = lane >> 4;
    const int j = lane & 15;

    const float4 q4 = Qf4[(size_t)wid * 16 + j];
    const int deg = min(cnt[wid], BCAP);
    const int* blist = bucket + (size_t)wid * BCAP;

    float acc0 = 0.f, acc1 = 0.f, acc2 = 0.f, acc3 = 0.f, den = 0.f;

    if (deg > 0) {
        const int nit = (deg + 3) >> 2;

        int e = slot;
        bool vc = e < deg;
        int sc = vc ? blist[e] : 0;
        int4 kv = KVi[(size_t)sc * 16 + j];

        for (int it = 1; it < nit; ++it) {
            const int en = (it << 2) + slot;
            const bool vn = en < deg;
            const int sn = vn ? blist[en] : 0;
            const int4 kvn = KVi[(size_t)sn * 16 + j];

            const float2 c0 = h2f(kv.x), c1 = h2f(kv.y), c2 = h2f(kv.z), c3 = h2f(kv.w);
            float p = q4.x * c0.x;
            p = fmaf(q4.y, c1.x, p);
            p = fmaf(q4.z, c2.x, p);
            p = fmaf(q4.w, c3.x, p);
            p += __shfl_xor(p, 1);
            p += __shfl_xor(p, 2);
            p += __shfl_xor(p, 4);
            const float ex = vc ? __expf(p) : 0.f;
            den += ex;
            acc0 = fmaf(ex, c0.y, acc0);
            acc1 = fmaf(ex, c1.y, acc1);
            acc2 = fmaf(ex, c2.y, acc2);
            acc3 = fmaf(ex, c3.y, acc3);

            kv = kvn; vc = vn;
        }
        {
            const float2 c0 = h2f(kv.x), c1 = h2f(kv.y), c2 = h2f(kv.z), c3 = h2f(kv.w);
            float p = q4.x * c0.x;
            p = fmaf(q4.y, c1.x, p);
            p = fmaf(q4.z, c2.x, p);
            p = fmaf(q4.w, c3.x, p);
            p += __shfl_xor(p, 1);
            p += __shfl_xor(p, 2);
            p += __shfl_xor(p, 4);
            const float ex = vc ? __expf(p) : 0.f;
            den += ex;
            acc0 = fmaf(ex, c0.y, acc0);
            acc1 = fmaf(ex, c1.y, acc1);
            acc2 = fmaf(ex, c2.y, acc2);
            acc3 = fmaf(ex, c3.y, acc3);
        }
    }

    acc0 += __shfl_xor(acc0, 16); acc0 += __shfl_xor(acc0, 32);
    acc1 += __shfl_xor(acc1, 16); acc1 += __shfl_xor(acc1, 32);
    acc2 += __shfl_xor(acc2, 16); acc2 += __shfl_xor(acc2, 32);
    acc3 += __shfl_xor(acc3, 16); acc3 += __shfl_xor(acc3, 32);
    den  += __shfl_xor(den, 16);  den  += __shfl_xor(den, 32);

    const float inv = (den > 0.f) ? (1.f / den) : 0.f;
    const float4 s4 = Sf4[(size_t)wid * 16 + j];
    float4 o;
    o.x = fmaxf(fmaf(acc0, inv, s4.x), 0.f);
    o.y = fmaxf(fmaf(acc1, inv, s4.y), 0.f);
    o.z = fmaxf(fmaf(acc2, inv, s4.z), 0.f);
    o.w = fmaxf(fmaf(acc3, inv, s4.w), 0.f);
    if (lane < 16) houtf4[(size_t)wid * 16 + j] = o;
}

// ---------------------------------------------------------------------------
// Attention layer 2: heads=1, d=32. One wave per node, 8 edges/iter,
// 2-deep pipeline.
// ---------------------------------------------------------------------------
__global__ void attn_h1(const float4* __restrict__ Qf4, const float4* __restrict__ Sf4,
                        const int4* __restrict__ KVi, const int* __restrict__ cnt,
                        const int* __restrict__ bucket, float4* __restrict__ outf4, int n)
{
    const int wid = (blockIdx.x * blockDim.x + threadIdx.x) >> 6;
    if (wid >= n) return;
    const int lane = threadIdx.x & 63;
    const int slot = lane >> 3;
    const int j = lane & 7;

    const float4 q4 = Qf4[(size_t)wid * 8 + j];
    const int deg = min(cnt[wid], BCAP);
    const int* blist = bucket + (size_t)wid * BCAP;

    float acc0 = 0.f, acc1 = 0.f, acc2 = 0.f, acc3 = 0.f, den = 0.f;

    if (deg > 0) {
        const int nit = (deg + 7) >> 3;

        int e = slot;
        bool vc = e < deg;
        int sc = vc ? blist[e] : 0;
        int4 kv = KVi[(size_t)sc * 8 + j];

        for (int it = 1; it < nit; ++it) {
            const int en = (it << 3) + slot;
            const bool vn = en < deg;
            const int sn = vn ? blist[en] : 0;
            const int4 kvn = KVi[(size_t)sn * 8 + j];

            const float2 c0 = h2f(kv.x), c1 = h2f(kv.y), c2 = h2f(kv.z), c3 = h2f(kv.w);
            float p = q4.x * c0.x;
            p = fmaf(q4.y, c1.x, p);
            p = fmaf(q4.z, c2.x, p);
            p = fmaf(q4.w, c3.x, p);
            p += __shfl_xor(p, 1);
            p += __shfl_xor(p, 2);
            p += __shfl_xor(p, 4);
            const float ex = vc ? __expf(p) : 0.f;
            den += ex;
            acc0 = fmaf(ex, c0.y, acc0);
            acc1 = fmaf(ex, c1.y, acc1);
            acc2 = fmaf(ex, c2.y, acc2);
            acc3 = fmaf(ex, c3.y, acc3);

            kv = kvn; vc = vn;
        }
        {
            const float2 c0 = h2f(kv.x), c1 = h2f(kv.y), c2 = h2f(kv.z), c3 = h2f(kv.w);
            float p = q4.x * c0.x;
            p = fmaf(q4.y, c1.x, p);
            p = fmaf(q4.z, c2.x, p);
            p = fmaf(q4.w, c3.x, p);
            p += __shfl_xor(p, 1);
            p += __shfl_xor(p, 2);
            p += __shfl_xor(p, 4);
            const float ex = vc ? __expf(p) : 0.f;
            den += ex;
            acc0 = fmaf(ex, c0.y, acc0);
            acc1 = fmaf(ex, c1.y, acc1);
            acc2 = fmaf(ex, c2.y, acc2);
            acc3 = fmaf(ex, c3.y, acc3);
        }
    }

    acc0 += __shfl_xor(acc0, 8); acc0 += __shfl_xor(acc0, 16); acc0 += __shfl_xor(acc0, 32);
    acc1 += __shfl_xor(acc1, 8); acc1 += __shfl_xor(acc1, 16); acc1 += __shfl_xor(acc1, 32);
    acc2 += __shfl_xor(acc2, 8); acc2 += __shfl_xor(acc2, 16); acc2 += __shfl_xor(acc2, 32);
    acc3 += __shfl_xor(acc3, 8); acc3 += __shfl_xor(acc3, 16); acc3 += __shfl_xor(acc3, 32);
    den  += __shfl_xor(den, 8);  den  += __shfl_xor(den, 16);  den  += __shfl_xor(den, 32);

    const float inv = (den > 0.f) ? (1.f / den) : 0.f;
    const float4 s4 = Sf4[(size_t)wid * 8 + j];
    float4 o;
    o.x = fmaf(acc0, inv, s4.x);
    o.y = fmaf(acc1, inv, s4.y);
    o.z = fmaf(acc2, inv, s4.z);
    o.w = fmaf(acc3, inv, s4.w);
    if (lane < 8) outf4[(size_t)wid * 8 + j] = o;
}

// ---------------------------------------------------------------------------
extern "C" void kernel_launch(void* const* d_in, const int* in_sizes, int n_in,
                              void* d_out, int out_size, void* d_ws, size_t ws_size,
                              hipStream_t stream)
{
    const float* x   = (const float*)d_in[0];
    const int* ei    = (const int*)d_in[1];
    const float* Wq1 = (const float*)d_in[2];  const float* bq1 = (const float*)d_in[3];
    const float* Wk1 = (const float*)d_in[4];  const float* bk1 = (const float*)d_in[5];
    const float* Wv1 = (const float*)d_in[6];  const float* bv1 = (const float*)d_in[7];
    const float* Ws1 = (const float*)d_in[8];  const float* bs1 = (const float*)d_in[9];
    const float* Wq2 = (const float*)d_in[10]; const float* bq2 = (const float*)d_in[11];
    const float* Wk2 = (const float*)d_in[12]; const float* bk2 = (const float*)d_in[13];
    const float* Wv2 = (const float*)d_in[14]; const float* bv2 = (const float*)d_in[15];
    const float* Ws2 = (const float*)d_in[16]; const float* bs2 = (const float*)d_in[17];

    const int n = in_sizes[0] / 64;   // 50000
    const int e = in_sizes[1] / 2;    // 800000
    const int* src = ei;
    const int* dst = ei + e;

    // workspace layout (layer2 q/s/kv alias layer1's)
    float*  q1  = (float*)d_ws;                        // n*64 f32
    float*  s1  = q1 + (size_t)n * 64;                 // n*64 f32
    __half* kv1 = (__half*)(s1 + (size_t)n * 64);      // n*128 fp16
    float*  h   = (float*)(kv1 + (size_t)n * 128);     // n*64 f32
    int*  cnt    = (int*)(h + (size_t)n * 64);         // n
    int*  bucket = cnt + n;                            // n*BCAP
    const int nbins = (n + 255) >> 8;                  // 196
    int2* pairs  = (int2*)(bucket + (size_t)n * BCAP); // nbins*BIN_CAP int2
    int*  bincur = (int*)(pairs + (size_t)nbins * BIN_CAP);  // nbins

    float* out = (float*)d_out;
    const int nblk  = (e + CHUNK - 1) / CHUNK;         // 196
    const int nb_gemm = (n + 63) / 64;

    // ---- adjacency build: fused counting sort (3 kernels) ----
    init_bincur<<<(nbins + 255) / 256, 256, 0, stream>>>(bincur, nbins);
    scatter_fused<<<nblk, 256, 0, stream>>>(src, dst, bincur, pairs, e, nbins);
    fine_bucket<<<nbins, 512, 0, stream>>>(pairs, bincur, cnt, bucket, n);

    // ---- layer 1 ----
    gemm_mfma<64><<<nb_gemm, 256, 0, stream>>>(
        x, n, Wq1, Wk1, Wv1, Ws1, bq1, bk1, bv1, bs1, q1, s1, kv1);
    attn_h2<<<(n + 3) / 4, 256, 0, stream>>>(
        (const float4*)q1, (const float4*)s1, (const int4*)kv1, cnt, bucket,
        (float4*)h, n);

    // ---- layer 2 (aliases layer-1 buffers) ----
    gemm_mfma<32><<<nb_gemm, 256, 0, stream>>>(
        h, n, Wq2, Wk2, Wv2, Ws2, bq2, bk2, bv2, bs2, q1, s1, kv1);
    attn_h1<<<(n + 3) / 4, 256, 0, stream>>>(
        (const float4*)q1, (const float4*)s1, (const int4*)kv1, cnt, bucket,
        (float4*)out, n);
}

// Round 11
// 123.013 us; speedup vs baseline: 1.4746x; 1.0245x over previous
//
#include <hip/hip_runtime.h>
#include <hip/hip_bf16.h>
#include <hip/hip_fp16.h>

#define CHUNK 4096       // edges per scatter block
#define BCAP 64          // bucket capacity per node (deg ~ Poisson(16))
#define BIN_CAP 6144     // pairs capacity per 256-node coarse bin (Poisson(4096), 32 sigma)

typedef _Float16 half8 __attribute__((ext_vector_type(8)));
typedef _Float16 half2v __attribute__((ext_vector_type(2)));
typedef float floatx4 __attribute__((ext_vector_type(4)));

__device__ __forceinline__ float2 h2f(int u)
{
    __half2 h = *reinterpret_cast<__half2*>(&u);
    return __half22float2(h);
}

__device__ __forceinline__ half2v as_h2(int u)
{
    union { int i; half2v h; } c; c.i = u; return c.h;
}

__device__ __forceinline__ int pack_h2(float a, float b)
{
    union { int i; half2v h; } c;
    c.h = (half2v){(_Float16)a, (_Float16)b};
    return c.i;
}

// ---------------------------------------------------------------------------
// MFMA fused GEMM: [Q|K|V|S] = X[n][64] @ W(64 x 4*HD) + b, per 64-node tile.
// Block = 256 thr / 4 waves; wave w owns matrix w (q,k,v,s). K=64, two k-steps.
//   q -> Q fp16 (pre-scaled by 1/sqrt(32)); s -> S fp16
//   k,v -> KV fp16 packed per int4: [k_c0,k_c0+1][k_c0+2,k_c0+3][v..][v..]
// X is f32 (layer 1) or fp16 (layer 2, = h).
// ---------------------------------------------------------------------------
template <int HD, bool XHALF>
__global__ __launch_bounds__(256) void gemm_mfma(
    const void* __restrict__ Xv, int n,
    const float* __restrict__ W0, const float* __restrict__ W1,
    const float* __restrict__ W2, const float* __restrict__ W3,
    const float* __restrict__ B0, const float* __restrict__ B1,
    const float* __restrict__ B2, const float* __restrict__ B3,
    __half* __restrict__ Q, __half* __restrict__ S, __half* __restrict__ KV)
{
    constexpr int NTW = HD / 16;
    const float qscale = 0.17677669529663687f;  // 1/sqrt(32)

    __shared__ _Float16 A_lds[64][72];
    __shared__ _Float16 B_lds[4 * HD][72];

    const int tid = threadIdx.x;
    const int n0 = blockIdx.x * 64;

    // ---- stage A: 64 nodes x 64 feats -> fp16 LDS ----
    {
        const int row = tid >> 2;
        const int cb  = (tid & 3) * 16;
        const int gnode = n0 + row;
        if (gnode < n) {
            if (XHALF) {
                const int4* xg = reinterpret_cast<const int4*>(
                    (const __half*)Xv + (size_t)gnode * 64 + cb);
                *reinterpret_cast<int4*>(&A_lds[row][cb])     = xg[0];
                *reinterpret_cast<int4*>(&A_lds[row][cb + 8]) = xg[1];
            } else {
                const float4* xg = reinterpret_cast<const float4*>(
                    (const float*)Xv + (size_t)gnode * 64 + cb);
#pragma unroll
                for (int t = 0; t < 4; ++t) {
                    const float4 v = xg[t];
                    A_lds[row][cb + 4 * t + 0] = (_Float16)v.x;
                    A_lds[row][cb + 4 * t + 1] = (_Float16)v.y;
                    A_lds[row][cb + 4 * t + 2] = (_Float16)v.z;
                    A_lds[row][cb + 4 * t + 3] = (_Float16)v.w;
                }
            }
        } else {
            const int4 z = {0, 0, 0, 0};
            *reinterpret_cast<int4*>(&A_lds[row][cb])     = z;
            *reinterpret_cast<int4*>(&A_lds[row][cb + 8]) = z;
        }
    }

    // ---- stage B transposed ----
    {
        const float* Ws[4] = {W0, W1, W2, W3};
#pragma unroll
        for (int m = 0; m < 4; ++m) {
            const float* W = Ws[m];
            for (int idx = tid; idx < 64 * HD; idx += 256) {
                const int k = idx / HD;
                const int jj = idx - k * HD;
                B_lds[m * HD + jj][k] = (_Float16)W[idx];
            }
        }
    }

    __syncthreads();

    const int w = tid >> 6;
    const int lane = tid & 63;
    const int lr = lane & 15;
    const int lk = (lane >> 4) * 8;

    half8 a[4][2];
#pragma unroll
    for (int mt = 0; mt < 4; ++mt)
#pragma unroll
        for (int ks = 0; ks < 2; ++ks)
            a[mt][ks] = *reinterpret_cast<const half8*>(&A_lds[mt * 16 + lr][ks * 32 + lk]);

    half8 b[NTW][2];
#pragma unroll
    for (int nt = 0; nt < NTW; ++nt)
#pragma unroll
        for (int ks = 0; ks < 2; ++ks)
            b[nt][ks] = *reinterpret_cast<const half8*>(&B_lds[w * HD + nt * 16 + lr][ks * 32 + lk]);

    floatx4 acc[4][NTW];
#pragma unroll
    for (int mt = 0; mt < 4; ++mt)
#pragma unroll
        for (int nt = 0; nt < NTW; ++nt)
            acc[mt][nt] = (floatx4){0.f, 0.f, 0.f, 0.f};

#pragma unroll
    for (int mt = 0; mt < 4; ++mt)
#pragma unroll
        for (int nt = 0; nt < NTW; ++nt) {
            acc[mt][nt] = __builtin_amdgcn_mfma_f32_16x16x32_f16(a[mt][0], b[nt][0], acc[mt][nt], 0, 0, 0);
            acc[mt][nt] = __builtin_amdgcn_mfma_f32_16x16x32_f16(a[mt][1], b[nt][1], acc[mt][nt], 0, 0, 0);
        }

    const float* Bv = (w == 0) ? B0 : (w == 1) ? B1 : (w == 2) ? B2 : B3;
    float bias[NTW];
#pragma unroll
    for (int nt = 0; nt < NTW; ++nt) bias[nt] = Bv[nt * 16 + lr];

#pragma unroll
    for (int mt = 0; mt < 4; ++mt) {
#pragma unroll
        for (int nt = 0; nt < NTW; ++nt) {
            const int jj = nt * 16 + lr;
#pragma unroll
            for (int r = 0; r < 4; ++r) {
                const int node = n0 + mt * 16 + (lane >> 4) * 4 + r;
                if (node < n) {
                    const float val = acc[mt][nt][r] + bias[nt];
                    if (w == 0)      Q[(size_t)node * HD + jj] = __float2half(val * qscale);
                    else if (w == 3) S[(size_t)node * HD + jj] = __float2half(val);
                    else             KV[(size_t)node * 2 * HD + (jj >> 2) * 8 + (w - 1) * 4 + (jj & 3)]
                                         = __float2half(val);
                }
            }
        }
    }
}

// ---------------------------------------------------------------------------
// Adjacency build (3 kernels): fixed-capacity coarse bins, block-claimed
// ranges (one global atomic per block x bin), LDS-cursor fine bucketing.
// ---------------------------------------------------------------------------
__global__ void init_bincur(int* __restrict__ bincur, int nbins)
{
    int i = blockIdx.x * blockDim.x + threadIdx.x;
    if (i < nbins) bincur[i] = i * BIN_CAP;
}

__global__ __launch_bounds__(256) void scatter_fused(
    const int* __restrict__ src, const int* __restrict__ dst,
    int* __restrict__ bincur, int2* __restrict__ pairs,
    int e, int nbins)
{
    __shared__ int lh[256];
    __shared__ int lbase[256];
    const int b = blockIdx.x;
    const int tid = threadIdx.x;
    if (tid < 256) lh[tid] = 0;
    __syncthreads();

    const int base = b * CHUNK;
    const int end = min(base + CHUNK, e);

    for (int i = base + tid * 4; i < end; i += 1024) {
        if (i + 4 <= end) {
            const int4 d4 = *reinterpret_cast<const int4*>(dst + i);
            atomicAdd(&lh[d4.x >> 8], 1);
            atomicAdd(&lh[d4.y >> 8], 1);
            atomicAdd(&lh[d4.z >> 8], 1);
            atomicAdd(&lh[d4.w >> 8], 1);
        } else {
            for (int jj = i; jj < end; ++jj) atomicAdd(&lh[dst[jj] >> 8], 1);
        }
    }
    __syncthreads();

    int mycnt = 0;
    if (tid < nbins) {
        mycnt = lh[tid];
        if (mycnt > 0) lbase[tid] = atomicAdd(&bincur[tid], mycnt);
    }
    __syncthreads();
    if (tid < 256) lh[tid] = 0;
    __syncthreads();

    for (int i = base + tid * 4; i < end; i += 1024) {
        if (i + 4 <= end) {
            const int4 d4 = *reinterpret_cast<const int4*>(dst + i);
            const int4 s4 = *reinterpret_cast<const int4*>(src + i);
            int bin, off;
            bin = d4.x >> 8; off = atomicAdd(&lh[bin], 1); pairs[lbase[bin] + off] = make_int2(d4.x, s4.x);
            bin = d4.y >> 8; off = atomicAdd(&lh[bin], 1); pairs[lbase[bin] + off] = make_int2(d4.y, s4.y);
            bin = d4.z >> 8; off = atomicAdd(&lh[bin], 1); pairs[lbase[bin] + off] = make_int2(d4.z, s4.z);
            bin = d4.w >> 8; off = atomicAdd(&lh[bin], 1); pairs[lbase[bin] + off] = make_int2(d4.w, s4.w);
        } else {
            for (int jj = i; jj < end; ++jj) {
                const int d = dst[jj];
                const int bin = d >> 8;
                const int off = atomicAdd(&lh[bin], 1);
                pairs[lbase[bin] + off] = make_int2(d, src[jj]);
            }
        }
    }
}

__global__ __launch_bounds__(512) void fine_bucket(
    const int2* __restrict__ pairs, const int* __restrict__ bincur,
    int* __restrict__ cnt, int* __restrict__ bucket, int n)
{
    __shared__ int cur[256];
    const int g = blockIdx.x;
    const int tid = threadIdx.x;
    const int n0 = g << 8;
    if (tid < 256) cur[tid] = 0;
    __syncthreads();

    const int e0 = g * BIN_CAP;
    const int e1 = bincur[g];
    for (int i = e0 + tid; i < e1; i += 512) {
        const int2 p = pairs[i];
        const int slot = atomicAdd(&cur[p.x - n0], 1);
        if (slot < BCAP) bucket[(size_t)p.x * BCAP + slot] = p.y;
    }
    __syncthreads();
    const int node = n0 + tid;
    if (tid < 256 && node < n) cnt[node] = cur[tid];
}

// ---------------------------------------------------------------------------
// Attention layer 1: heads=2, d=32. One wave per node, 4 edges/iter,
// 2-deep pipeline. slot = lane>>4, j = lane&15 (4 channels/lane).
// KV int4 = [k01][k23][v01][v23]; dot via v_dot2_f32_f16.
// Q,S fp16; output h fp16.
// ---------------------------------------------------------------------------
__global__ void attn_h2(const __half* __restrict__ Qh, const __half* __restrict__ Sh,
                        const int4* __restrict__ KVi, const int* __restrict__ cnt,
                        const int* __restrict__ bucket, __half* __restrict__ Hh, int n)
{
    const int wid = (blockIdx.x * blockDim.x + threadIdx.x) >> 6;
    if (wid >= n) return;
    const int lane = threadIdx.x & 63;
    const int slot = lane >> 4;
    const int j = lane & 15;

    const int2 qi = reinterpret_cast<const int2*>(Qh + (size_t)wid * 64)[j];
    const half2v q01 = as_h2(qi.x), q23 = as_h2(qi.y);

    const int deg = min(cnt[wid], BCAP);
    const int* blist = bucket + (size_t)wid * BCAP;

    float acc0 = 0.f, acc1 = 0.f, acc2 = 0.f, acc3 = 0.f, den = 0.f;

    if (deg > 0) {
        const int nit = (deg + 3) >> 2;

        int e = slot;
        bool vc = e < deg;
        int sc = vc ? blist[e] : 0;
        int4 kv = KVi[(size_t)sc * 16 + j];

        for (int it = 1; it < nit; ++it) {
            const int en = (it << 2) + slot;
            const bool vn = en < deg;
            const int sn = vn ? blist[en] : 0;
            const int4 kvn = KVi[(size_t)sn * 16 + j];

            float p = __builtin_amdgcn_fdot2(as_h2(kv.x), q01,
                      __builtin_amdgcn_fdot2(as_h2(kv.y), q23, 0.f, false), false);
            p += __shfl_xor(p, 1);
            p += __shfl_xor(p, 2);
            p += __shfl_xor(p, 4);
            const float ex = vc ? __expf(p) : 0.f;
            const float2 v01 = h2f(kv.z), v23 = h2f(kv.w);
            den += ex;
            acc0 = fmaf(ex, v01.x, acc0);
            acc1 = fmaf(ex, v01.y, acc1);
            acc2 = fmaf(ex, v23.x, acc2);
            acc3 = fmaf(ex, v23.y, acc3);

            kv = kvn; vc = vn;
        }
        {
            float p = __builtin_amdgcn_fdot2(as_h2(kv.x), q01,
                      __builtin_amdgcn_fdot2(as_h2(kv.y), q23, 0.f, false), false);
            p += __shfl_xor(p, 1);
            p += __shfl_xor(p, 2);
            p += __shfl_xor(p, 4);
            const float ex = vc ? __expf(p) : 0.f;
            const float2 v01 = h2f(kv.z), v23 = h2f(kv.w);
            den += ex;
            acc0 = fmaf(ex, v01.x, acc0);
            acc1 = fmaf(ex, v01.y, acc1);
            acc2 = fmaf(ex, v23.x, acc2);
            acc3 = fmaf(ex, v23.y, acc3);
        }
    }

    acc0 += __shfl_xor(acc0, 16); acc0 += __shfl_xor(acc0, 32);
    acc1 += __shfl_xor(acc1, 16); acc1 += __shfl_xor(acc1, 32);
    acc2 += __shfl_xor(acc2, 16); acc2 += __shfl_xor(acc2, 32);
    acc3 += __shfl_xor(acc3, 16); acc3 += __shfl_xor(acc3, 32);
    den  += __shfl_xor(den, 16);  den  += __shfl_xor(den, 32);

    const float inv = (den > 0.f) ? (1.f / den) : 0.f;
    const int2 si = reinterpret_cast<const int2*>(Sh + (size_t)wid * 64)[j];
    const float2 s01 = h2f(si.x), s23 = h2f(si.y);
    const float o0 = fmaxf(fmaf(acc0, inv, s01.x), 0.f);
    const float o1 = fmaxf(fmaf(acc1, inv, s01.y), 0.f);
    const float o2 = fmaxf(fmaf(acc2, inv, s23.x), 0.f);
    const float o3 = fmaxf(fmaf(acc3, inv, s23.y), 0.f);
    if (lane < 16) {
        int2 ov = {pack_h2(o0, o1), pack_h2(o2, o3)};
        reinterpret_cast<int2*>(Hh + (size_t)wid * 64)[j] = ov;
    }
}

// ---------------------------------------------------------------------------
// Attention layer 2: heads=1, d=32. One wave per node, 8 edges/iter,
// 2-deep pipeline. slot = lane>>3, j = lane&7. Output f32 (d_out).
// ---------------------------------------------------------------------------
__global__ void attn_h1(const __half* __restrict__ Qh, const __half* __restrict__ Sh,
                        const int4* __restrict__ KVi, const int* __restrict__ cnt,
                        const int* __restrict__ bucket, float4* __restrict__ outf4, int n)
{
    const int wid = (blockIdx.x * blockDim.x + threadIdx.x) >> 6;
    if (wid >= n) return;
    const int lane = threadIdx.x & 63;
    const int slot = lane >> 3;
    const int j = lane & 7;

    const int2 qi = reinterpret_cast<const int2*>(Qh + (size_t)wid * 32)[j];
    const half2v q01 = as_h2(qi.x), q23 = as_h2(qi.y);

    const int deg = min(cnt[wid], BCAP);
    const int* blist = bucket + (size_t)wid * BCAP;

    float acc0 = 0.f, acc1 = 0.f, acc2 = 0.f, acc3 = 0.f, den = 0.f;

    if (deg > 0) {
        const int nit = (deg + 7) >> 3;

        int e = slot;
        bool vc = e < deg;
        int sc = vc ? blist[e] : 0;
        int4 kv = KVi[(size_t)sc * 8 + j];

        for (int it = 1; it < nit; ++it) {
            const int en = (it << 3) + slot;
            const bool vn = en < deg;
            const int sn = vn ? blist[en] : 0;
            const int4 kvn = KVi[(size_t)sn * 8 + j];

            float p = __builtin_amdgcn_fdot2(as_h2(kv.x), q01,
                      __builtin_amdgcn_fdot2(as_h2(kv.y), q23, 0.f, false), false);
            p += __shfl_xor(p, 1);
            p += __shfl_xor(p, 2);
            p += __shfl_xor(p, 4);
            const float ex = vc ? __expf(p) : 0.f;
            const float2 v01 = h2f(kv.z), v23 = h2f(kv.w);
            den += ex;
            acc0 = fmaf(ex, v01.x, acc0);
            acc1 = fmaf(ex, v01.y, acc1);
            acc2 = fmaf(ex, v23.x, acc2);
            acc3 = fmaf(ex, v23.y, acc3);

            kv = kvn; vc = vn;
        }
        {
            float p = __builtin_amdgcn_fdot2(as_h2(kv.x), q01,
                      __builtin_amdgcn_fdot2(as_h2(kv.y), q23, 0.f, false), false);
            p += __shfl_xor(p, 1);
            p += __shfl_xor(p, 2);
            p += __shfl_xor(p, 4);
            const float ex = vc ? __expf(p) : 0.f;
            const float2 v01 = h2f(kv.z), v23 = h2f(kv.w);
            den += ex;
            acc0 = fmaf(ex, v01.x, acc0);
            acc1 = fmaf(ex, v01.y, acc1);
            acc2 = fmaf(ex, v23.x, acc2);
            acc3 = fmaf(ex, v23.y, acc3);
        }
    }

    acc0 += __shfl_xor(acc0, 8); acc0 += __shfl_xor(acc0, 16); acc0 += __shfl_xor(acc0, 32);
    acc1 += __shfl_xor(acc1, 8); acc1 += __shfl_xor(acc1, 16); acc1 += __shfl_xor(acc1, 32);
    acc2 += __shfl_xor(acc2, 8); acc2 += __shfl_xor(acc2, 16); acc2 += __shfl_xor(acc2, 32);
    acc3 += __shfl_xor(acc3, 8); acc3 += __shfl_xor(acc3, 16); acc3 += __shfl_xor(acc3, 32);
    den  += __shfl_xor(den, 8);  den  += __shfl_xor(den, 16);  den  += __shfl_xor(den, 32);

    const float inv = (den > 0.f) ? (1.f / den) : 0.f;
    const int2 si = reinterpret_cast<const int2*>(Sh + (size_t)wid * 32)[j];
    const float2 s01 = h2f(si.x), s23 = h2f(si.y);
    float4 o;
    o.x = fmaf(acc0, inv, s01.x);
    o.y = fmaf(acc1, inv, s01.y);
    o.z = fmaf(acc2, inv, s23.x);
    o.w = fmaf(acc3, inv, s23.y);
    if (lane < 8) outf4[(size_t)wid * 8 + j] = o;
}

// ---------------------------------------------------------------------------
extern "C" void kernel_launch(void* const* d_in, const int* in_sizes, int n_in,
                              void* d_out, int out_size, void* d_ws, size_t ws_size,
                              hipStream_t stream)
{
    const float* x   = (const float*)d_in[0];
    const int* ei    = (const int*)d_in[1];
    const float* Wq1 = (const float*)d_in[2];  const float* bq1 = (const float*)d_in[3];
    const float* Wk1 = (const float*)d_in[4];  const float* bk1 = (const float*)d_in[5];
    const float* Wv1 = (const float*)d_in[6];  const float* bv1 = (const float*)d_in[7];
    const float* Ws1 = (const float*)d_in[8];  const float* bs1 = (const float*)d_in[9];
    const float* Wq2 = (const float*)d_in[10]; const float* bq2 = (const float*)d_in[11];
    const float* Wk2 = (const float*)d_in[12]; const float* bk2 = (const float*)d_in[13];
    const float* Wv2 = (const float*)d_in[14]; const float* bv2 = (const float*)d_in[15];
    const float* Ws2 = (const float*)d_in[16]; const float* bs2 = (const float*)d_in[17];

    const int n = in_sizes[0] / 64;   // 50000
    const int e = in_sizes[1] / 2;    // 800000
    const int* src = ei;
    const int* dst = ei + e;

    // workspace layout (all fp16 activations; layer2 q/s/kv alias layer1's)
    __half* q1  = (__half*)d_ws;                       // n*64 fp16
    __half* s1  = q1 + (size_t)n * 64;                 // n*64 fp16
    __half* kv1 = s1 + (size_t)n * 64;                 // n*128 fp16
    __half* hh  = kv1 + (size_t)n * 128;               // n*64 fp16
    int*  cnt    = (int*)(hh + (size_t)n * 64);        // n
    int*  bucket = cnt + n;                            // n*BCAP
    const int nbins = (n + 255) >> 8;                  // 196
    int2* pairs  = (int2*)(bucket + (size_t)n * BCAP); // nbins*BIN_CAP int2
    int*  bincur = (int*)(pairs + (size_t)nbins * BIN_CAP);  // nbins

    float* out = (float*)d_out;
    const int nblk  = (e + CHUNK - 1) / CHUNK;         // 196
    const int nb_gemm = (n + 63) / 64;

    // ---- adjacency build: fused counting sort (3 kernels) ----
    init_bincur<<<(nbins + 255) / 256, 256, 0, stream>>>(bincur, nbins);
    scatter_fused<<<nblk, 256, 0, stream>>>(src, dst, bincur, pairs, e, nbins);
    fine_bucket<<<nbins, 512, 0, stream>>>(pairs, bincur, cnt, bucket, n);

    // ---- layer 1 ----
    gemm_mfma<64, false><<<nb_gemm, 256, 0, stream>>>(
        x, n, Wq1, Wk1, Wv1, Ws1, bq1, bk1, bv1, bs1, q1, s1, kv1);
    attn_h2<<<(n + 3) / 4, 256, 0, stream>>>(
        q1, s1, (const int4*)kv1, cnt, bucket, hh, n);

    // ---- layer 2 (aliases layer-1 buffers; input h is fp16) ----
    gemm_mfma<32, true><<<nb_gemm, 256, 0, stream>>>(
        hh, n, Wq2, Wk2, Wv2, Ws2, bq2, bk2, bv2, bs2, q1, s1, kv1);
    attn_h1<<<(n + 3) / 4, 256, 0, stream>>>(
        q1, s1, (const int4*)kv1, cnt, bucket, (float4*)out, n);
}

// Round 12
// 114.671 us; speedup vs baseline: 1.5819x; 1.0727x over previous
//
#include <hip/hip_runtime.h>
#include <hip/hip_bf16.h>
#include <hip/hip_fp16.h>

#define CHUNK 4096       // edges per scatter block
#define BCAP 64          // bucket capacity per node (deg ~ Poisson(16))
#define BIN_CAP 6144     // pairs capacity per 256-node coarse bin (Poisson(4096), 32 sigma)

typedef _Float16 half8 __attribute__((ext_vector_type(8)));
typedef _Float16 half2v __attribute__((ext_vector_type(2)));
typedef float floatx4 __attribute__((ext_vector_type(4)));

__device__ __forceinline__ float2 h2f(int u)
{
    __half2 h = *reinterpret_cast<__half2*>(&u);
    return __half22float2(h);
}

__device__ __forceinline__ half2v as_h2(int u)
{
    union { int i; half2v h; } c; c.i = u; return c.h;
}

__device__ __forceinline__ int pack_h2(float a, float b)
{
    union { int i; half2v h; } c;
    c.h = (half2v){(_Float16)a, (_Float16)b};
    return c.i;
}

// ---------------------------------------------------------------------------
// MFMA fused GEMM layer 1: [Q|K|V|S] = X[n][64] @ W + b, per 64-node tile.
// Also performs bincur init (block 0) so init_bincur launch is removed.
//   q -> Q fp16 (pre-scaled); s -> S fp16; k,v -> KV packed [k01][k23][v01][v23]
// ---------------------------------------------------------------------------
__global__ __launch_bounds__(256) void gemm1(
    const float* __restrict__ X, int n,
    const float* __restrict__ W0, const float* __restrict__ W1,
    const float* __restrict__ W2, const float* __restrict__ W3,
    const float* __restrict__ B0, const float* __restrict__ B1,
    const float* __restrict__ B2, const float* __restrict__ B3,
    __half* __restrict__ Q, __half* __restrict__ S, __half* __restrict__ KV,
    int* __restrict__ bincur, int nbins)
{
    constexpr int HD = 64;
    constexpr int NTW = 4;
    const float qscale = 0.17677669529663687f;  // 1/sqrt(32)

    __shared__ _Float16 A_lds[64][72];
    __shared__ _Float16 B_lds[4 * HD][72];

    const int tid = threadIdx.x;
    const int n0 = blockIdx.x * 64;

    if (blockIdx.x == 0 && tid < nbins) bincur[tid] = tid * BIN_CAP;

    {
        const int row = tid >> 2;
        const int cb  = (tid & 3) * 16;
        const int gnode = n0 + row;
        if (gnode < n) {
            const float4* xg = reinterpret_cast<const float4*>(X + (size_t)gnode * 64 + cb);
#pragma unroll
            for (int t = 0; t < 4; ++t) {
                const float4 v = xg[t];
                A_lds[row][cb + 4 * t + 0] = (_Float16)v.x;
                A_lds[row][cb + 4 * t + 1] = (_Float16)v.y;
                A_lds[row][cb + 4 * t + 2] = (_Float16)v.z;
                A_lds[row][cb + 4 * t + 3] = (_Float16)v.w;
            }
        } else {
            const int4 z = {0, 0, 0, 0};
            *reinterpret_cast<int4*>(&A_lds[row][cb])     = z;
            *reinterpret_cast<int4*>(&A_lds[row][cb + 8]) = z;
        }
    }

    {
        const float* Ws[4] = {W0, W1, W2, W3};
#pragma unroll
        for (int m = 0; m < 4; ++m) {
            const float* W = Ws[m];
            for (int idx = tid; idx < 64 * HD; idx += 256) {
                const int k = idx / HD;
                const int jj = idx - k * HD;
                B_lds[m * HD + jj][k] = (_Float16)W[idx];
            }
        }
    }

    __syncthreads();

    const int w = tid >> 6;
    const int lane = tid & 63;
    const int lr = lane & 15;
    const int lk = (lane >> 4) * 8;

    half8 a[4][2];
#pragma unroll
    for (int mt = 0; mt < 4; ++mt)
#pragma unroll
        for (int ks = 0; ks < 2; ++ks)
            a[mt][ks] = *reinterpret_cast<const half8*>(&A_lds[mt * 16 + lr][ks * 32 + lk]);

    half8 b[NTW][2];
#pragma unroll
    for (int nt = 0; nt < NTW; ++nt)
#pragma unroll
        for (int ks = 0; ks < 2; ++ks)
            b[nt][ks] = *reinterpret_cast<const half8*>(&B_lds[w * HD + nt * 16 + lr][ks * 32 + lk]);

    floatx4 acc[4][NTW];
#pragma unroll
    for (int mt = 0; mt < 4; ++mt)
#pragma unroll
        for (int nt = 0; nt < NTW; ++nt)
            acc[mt][nt] = (floatx4){0.f, 0.f, 0.f, 0.f};

#pragma unroll
    for (int mt = 0; mt < 4; ++mt)
#pragma unroll
        for (int nt = 0; nt < NTW; ++nt) {
            acc[mt][nt] = __builtin_amdgcn_mfma_f32_16x16x32_f16(a[mt][0], b[nt][0], acc[mt][nt], 0, 0, 0);
            acc[mt][nt] = __builtin_amdgcn_mfma_f32_16x16x32_f16(a[mt][1], b[nt][1], acc[mt][nt], 0, 0, 0);
        }

    const float* Bv = (w == 0) ? B0 : (w == 1) ? B1 : (w == 2) ? B2 : B3;
    float bias[NTW];
#pragma unroll
    for (int nt = 0; nt < NTW; ++nt) bias[nt] = Bv[nt * 16 + lr];

#pragma unroll
    for (int mt = 0; mt < 4; ++mt) {
#pragma unroll
        for (int nt = 0; nt < NTW; ++nt) {
            const int jj = nt * 16 + lr;
#pragma unroll
            for (int r = 0; r < 4; ++r) {
                const int node = n0 + mt * 16 + (lane >> 4) * 4 + r;
                if (node < n) {
                    const float val = acc[mt][nt][r] + bias[nt];
                    if (w == 0)      Q[(size_t)node * HD + jj] = __float2half(val * qscale);
                    else if (w == 3) S[(size_t)node * HD + jj] = __float2half(val);
                    else             KV[(size_t)node * 2 * HD + (jj >> 2) * 8 + (w - 1) * 4 + (jj & 3)]
                                         = __float2half(val);
                }
            }
        }
    }
}

// ---------------------------------------------------------------------------
// Adjacency build: fixed-capacity coarse bins, block-claimed ranges.
// ---------------------------------------------------------------------------
__global__ __launch_bounds__(256) void scatter_fused(
    const int* __restrict__ src, const int* __restrict__ dst,
    int* __restrict__ bincur, int2* __restrict__ pairs,
    int e, int nbins)
{
    __shared__ int lh[256];
    __shared__ int lbase[256];
    const int b = blockIdx.x;
    const int tid = threadIdx.x;
    if (tid < 256) lh[tid] = 0;
    __syncthreads();

    const int base = b * CHUNK;
    const int end = min(base + CHUNK, e);

    for (int i = base + tid * 4; i < end; i += 1024) {
        if (i + 4 <= end) {
            const int4 d4 = *reinterpret_cast<const int4*>(dst + i);
            atomicAdd(&lh[d4.x >> 8], 1);
            atomicAdd(&lh[d4.y >> 8], 1);
            atomicAdd(&lh[d4.z >> 8], 1);
            atomicAdd(&lh[d4.w >> 8], 1);
        } else {
            for (int jj = i; jj < end; ++jj) atomicAdd(&lh[dst[jj] >> 8], 1);
        }
    }
    __syncthreads();

    int mycnt = 0;
    if (tid < nbins) {
        mycnt = lh[tid];
        if (mycnt > 0) lbase[tid] = atomicAdd(&bincur[tid], mycnt);
    }
    __syncthreads();
    if (tid < 256) lh[tid] = 0;
    __syncthreads();

    for (int i = base + tid * 4; i < end; i += 1024) {
        if (i + 4 <= end) {
            const int4 d4 = *reinterpret_cast<const int4*>(dst + i);
            const int4 s4 = *reinterpret_cast<const int4*>(src + i);
            int bin, off;
            bin = d4.x >> 8; off = atomicAdd(&lh[bin], 1); pairs[lbase[bin] + off] = make_int2(d4.x, s4.x);
            bin = d4.y >> 8; off = atomicAdd(&lh[bin], 1); pairs[lbase[bin] + off] = make_int2(d4.y, s4.y);
            bin = d4.z >> 8; off = atomicAdd(&lh[bin], 1); pairs[lbase[bin] + off] = make_int2(d4.z, s4.z);
            bin = d4.w >> 8; off = atomicAdd(&lh[bin], 1); pairs[lbase[bin] + off] = make_int2(d4.w, s4.w);
        } else {
            for (int jj = i; jj < end; ++jj) {
                const int d = dst[jj];
                const int bin = d >> 8;
                const int off = atomicAdd(&lh[bin], 1);
                pairs[lbase[bin] + off] = make_int2(d, src[jj]);
            }
        }
    }
}

__global__ __launch_bounds__(512) void fine_bucket(
    const int2* __restrict__ pairs, const int* __restrict__ bincur,
    int* __restrict__ cnt, int* __restrict__ bucket, int n)
{
    __shared__ int cur[256];
    const int g = blockIdx.x;
    const int tid = threadIdx.x;
    const int n0 = g << 8;
    if (tid < 256) cur[tid] = 0;
    __syncthreads();

    const int e0 = g * BIN_CAP;
    const int e1 = bincur[g];
    for (int i = e0 + tid; i < e1; i += 512) {
        const int2 p = pairs[i];
        const int slot = atomicAdd(&cur[p.x - n0], 1);
        if (slot < BCAP) bucket[(size_t)p.x * BCAP + slot] = p.y;
    }
    __syncthreads();
    const int node = n0 + tid;
    if (tid < 256 && node < n) cnt[node] = cur[tid];
}

// ---------------------------------------------------------------------------
// FUSED layer-1 attention + layer-2 GEMM.
// Block = 1024 thr / 16 waves, 64 nodes. Phase 1: wave w does attention for
// nodes n0+4w..n0+4w+3 (slot=lane>>4 edge slot, j=lane&15 -> channels 4j..4j+3),
// writing relu(att+s) fp16 into the MFMA A-tile in LDS. Phase 2: the block
// computes [Q2|K2|V2|S2] = h @ W2 + b2 (32 16x16 tiles, 2 per wave).
// ---------------------------------------------------------------------------
__global__ __launch_bounds__(1024, 8) void attn1_gemm2(
    const __half* __restrict__ Q1, const __half* __restrict__ S1,
    const int4* __restrict__ KV1, const int* __restrict__ cnt,
    const int* __restrict__ bucket,
    const float* __restrict__ W0, const float* __restrict__ W1,
    const float* __restrict__ W2, const float* __restrict__ W3,
    const float* __restrict__ B0, const float* __restrict__ B1,
    const float* __restrict__ B2, const float* __restrict__ B3,
    __half* __restrict__ Q2, __half* __restrict__ S2, __half* __restrict__ KV2,
    int n)
{
    const float qscale = 0.17677669529663687f;  // 1/sqrt(32)

    __shared__ _Float16 A_lds[64][72];          // h tile (fp16, padded)
    __shared__ _Float16 B_lds[128][72];         // W2^T: [m*32+jj][k]

    const int tid = threadIdx.x;
    const int n0 = blockIdx.x * 64;
    const int w = tid >> 6;
    const int lane = tid & 63;

    // ---- stage W2^T (4 x 64x32 f32 -> fp16) ----
    {
        const float* Ws[4] = {W0, W1, W2, W3};
#pragma unroll
        for (int m = 0; m < 4; ++m) {
            const float* W = Ws[m];
            for (int idx = tid; idx < 64 * 32; idx += 1024) {
                const int k = idx >> 5;
                const int jj = idx & 31;
                B_lds[m * 32 + jj][k] = (_Float16)W[idx];
            }
        }
    }

    // ---- phase 1: attention, 4 nodes per wave ----
    const int slot = lane >> 4;
    const int j = lane & 15;

    for (int nd = 0; nd < 4; ++nd) {
        const int wid = n0 + w * 4 + nd;
        float o0 = 0.f, o1 = 0.f, o2 = 0.f, o3 = 0.f;
        if (wid < n) {
            const int2 qi = reinterpret_cast<const int2*>(Q1 + (size_t)wid * 64)[j];
            const half2v q01 = as_h2(qi.x), q23 = as_h2(qi.y);
            const int deg = min(cnt[wid], BCAP);
            const int* blist = bucket + (size_t)wid * BCAP;

            float acc0 = 0.f, acc1 = 0.f, acc2 = 0.f, acc3 = 0.f, den = 0.f;
            if (deg > 0) {
                const int nit = (deg + 3) >> 2;
                int e = slot;
                bool vc = e < deg;
                int sc = vc ? blist[e] : 0;
                int4 kv = KV1[(size_t)sc * 16 + j];

                for (int it = 1; it < nit; ++it) {
                    const int en = (it << 2) + slot;
                    const bool vn = en < deg;
                    const int sn = vn ? blist[en] : 0;
                    const int4 kvn = KV1[(size_t)sn * 16 + j];

                    float p = __builtin_amdgcn_fdot2(as_h2(kv.x), q01,
                              __builtin_amdgcn_fdot2(as_h2(kv.y), q23, 0.f, false), false);
                    p += __shfl_xor(p, 1);
                    p += __shfl_xor(p, 2);
                    p += __shfl_xor(p, 4);
                    const float ex = vc ? __expf(p) : 0.f;
                    const float2 v01 = h2f(kv.z), v23 = h2f(kv.w);
                    den += ex;
                    acc0 = fmaf(ex, v01.x, acc0);
                    acc1 = fmaf(ex, v01.y, acc1);
                    acc2 = fmaf(ex, v23.x, acc2);
                    acc3 = fmaf(ex, v23.y, acc3);
                    kv = kvn; vc = vn;
                }
                {
                    float p = __builtin_amdgcn_fdot2(as_h2(kv.x), q01,
                              __builtin_amdgcn_fdot2(as_h2(kv.y), q23, 0.f, false), false);
                    p += __shfl_xor(p, 1);
                    p += __shfl_xor(p, 2);
                    p += __shfl_xor(p, 4);
                    const float ex = vc ? __expf(p) : 0.f;
                    const float2 v01 = h2f(kv.z), v23 = h2f(kv.w);
                    den += ex;
                    acc0 = fmaf(ex, v01.x, acc0);
                    acc1 = fmaf(ex, v01.y, acc1);
                    acc2 = fmaf(ex, v23.x, acc2);
                    acc3 = fmaf(ex, v23.y, acc3);
                }
            }
            acc0 += __shfl_xor(acc0, 16); acc0 += __shfl_xor(acc0, 32);
            acc1 += __shfl_xor(acc1, 16); acc1 += __shfl_xor(acc1, 32);
            acc2 += __shfl_xor(acc2, 16); acc2 += __shfl_xor(acc2, 32);
            acc3 += __shfl_xor(acc3, 16); acc3 += __shfl_xor(acc3, 32);
            den  += __shfl_xor(den, 16);  den  += __shfl_xor(den, 32);

            const float inv = (den > 0.f) ? (1.f / den) : 0.f;
            const int2 si = reinterpret_cast<const int2*>(S1 + (size_t)wid * 64)[j];
            const float2 s01 = h2f(si.x), s23 = h2f(si.y);
            o0 = fmaxf(fmaf(acc0, inv, s01.x), 0.f);
            o1 = fmaxf(fmaf(acc1, inv, s01.y), 0.f);
            o2 = fmaxf(fmaf(acc2, inv, s23.x), 0.f);
            o3 = fmaxf(fmaf(acc3, inv, s23.y), 0.f);
        }
        if (lane < 16) {
            int2 ov = {pack_h2(o0, o1), pack_h2(o2, o3)};
            *reinterpret_cast<int2*>(&A_lds[w * 4 + nd][4 * j]) = ov;
        }
    }

    __syncthreads();

    // ---- phase 2: gemm2, 2 tiles per wave (32 tiles: [mt 0..3][ntg 0..7]) ----
    const int lr = lane & 15;
    const int lk = (lane >> 4) * 8;

#pragma unroll
    for (int tt = 0; tt < 2; ++tt) {
        const int t = w + tt * 16;
        const int mt = t >> 3;
        const int ntg = t & 7;
        const int m = ntg >> 1;
        const int nt = ntg & 1;

        const half8 af0 = *reinterpret_cast<const half8*>(&A_lds[mt * 16 + lr][lk]);
        const half8 af1 = *reinterpret_cast<const half8*>(&A_lds[mt * 16 + lr][32 + lk]);
        const half8 bf0 = *reinterpret_cast<const half8*>(&B_lds[ntg * 16 + lr][lk]);
        const half8 bf1 = *reinterpret_cast<const half8*>(&B_lds[ntg * 16 + lr][32 + lk]);

        floatx4 acc = (floatx4){0.f, 0.f, 0.f, 0.f};
        acc = __builtin_amdgcn_mfma_f32_16x16x32_f16(af0, bf0, acc, 0, 0, 0);
        acc = __builtin_amdgcn_mfma_f32_16x16x32_f16(af1, bf1, acc, 0, 0, 0);

        const float* Bv = (m == 0) ? B0 : (m == 1) ? B1 : (m == 2) ? B2 : B3;
        const int jj = nt * 16 + lr;
        const float bias = Bv[jj];

#pragma unroll
        for (int r = 0; r < 4; ++r) {
            const int node = n0 + mt * 16 + (lane >> 4) * 4 + r;
            if (node < n) {
                const float val = acc[r] + bias;
                if (m == 0)      Q2[(size_t)node * 32 + jj] = __float2half(val * qscale);
                else if (m == 3) S2[(size_t)node * 32 + jj] = __float2half(val);
                else             KV2[(size_t)node * 64 + (jj >> 2) * 8 + (m - 1) * 4 + (jj & 3)]
                                     = __float2half(val);
            }
        }
    }
}

// ---------------------------------------------------------------------------
// Attention layer 2: heads=1, d=32. One wave per node, 8 edges/iter,
// 2-deep pipeline. Output f32 (d_out).
// ---------------------------------------------------------------------------
__global__ void attn_h1(const __half* __restrict__ Qh, const __half* __restrict__ Sh,
                        const int4* __restrict__ KVi, const int* __restrict__ cnt,
                        const int* __restrict__ bucket, float4* __restrict__ outf4, int n)
{
    const int wid = (blockIdx.x * blockDim.x + threadIdx.x) >> 6;
    if (wid >= n) return;
    const int lane = threadIdx.x & 63;
    const int slot = lane >> 3;
    const int j = lane & 7;

    const int2 qi = reinterpret_cast<const int2*>(Qh + (size_t)wid * 32)[j];
    const half2v q01 = as_h2(qi.x), q23 = as_h2(qi.y);

    const int deg = min(cnt[wid], BCAP);
    const int* blist = bucket + (size_t)wid * BCAP;

    float acc0 = 0.f, acc1 = 0.f, acc2 = 0.f, acc3 = 0.f, den = 0.f;

    if (deg > 0) {
        const int nit = (deg + 7) >> 3;

        int e = slot;
        bool vc = e < deg;
        int sc = vc ? blist[e] : 0;
        int4 kv = KVi[(size_t)sc * 8 + j];

        for (int it = 1; it < nit; ++it) {
            const int en = (it << 3) + slot;
            const bool vn = en < deg;
            const int sn = vn ? blist[en] : 0;
            const int4 kvn = KVi[(size_t)sn * 8 + j];

            float p = __builtin_amdgcn_fdot2(as_h2(kv.x), q01,
                      __builtin_amdgcn_fdot2(as_h2(kv.y), q23, 0.f, false), false);
            p += __shfl_xor(p, 1);
            p += __shfl_xor(p, 2);
            p += __shfl_xor(p, 4);
            const float ex = vc ? __expf(p) : 0.f;
            const float2 v01 = h2f(kv.z), v23 = h2f(kv.w);
            den += ex;
            acc0 = fmaf(ex, v01.x, acc0);
            acc1 = fmaf(ex, v01.y, acc1);
            acc2 = fmaf(ex, v23.x, acc2);
            acc3 = fmaf(ex, v23.y, acc3);

            kv = kvn; vc = vn;
        }
        {
            float p = __builtin_amdgcn_fdot2(as_h2(kv.x), q01,
                      __builtin_amdgcn_fdot2(as_h2(kv.y), q23, 0.f, false), false);
            p += __shfl_xor(p, 1);
            p += __shfl_xor(p, 2);
            p += __shfl_xor(p, 4);
            const float ex = vc ? __expf(p) : 0.f;
            const float2 v01 = h2f(kv.z), v23 = h2f(kv.w);
            den += ex;
            acc0 = fmaf(ex, v01.x, acc0);
            acc1 = fmaf(ex, v01.y, acc1);
            acc2 = fmaf(ex, v23.x, acc2);
            acc3 = fmaf(ex, v23.y, acc3);
        }
    }

    acc0 += __shfl_xor(acc0, 8); acc0 += __shfl_xor(acc0, 16); acc0 += __shfl_xor(acc0, 32);
    acc1 += __shfl_xor(acc1, 8); acc1 += __shfl_xor(acc1, 16); acc1 += __shfl_xor(acc1, 32);
    acc2 += __shfl_xor(acc2, 8); acc2 += __shfl_xor(acc2, 16); acc2 += __shfl_xor(acc2, 32);
    acc3 += __shfl_xor(acc3, 8); acc3 += __shfl_xor(acc3, 16); acc3 += __shfl_xor(acc3, 32);
    den  += __shfl_xor(den, 8);  den  += __shfl_xor(den, 16);  den  += __shfl_xor(den, 32);

    const float inv = (den > 0.f) ? (1.f / den) : 0.f;
    const int2 si = reinterpret_cast<const int2*>(Sh + (size_t)wid * 32)[j];
    const float2 s01 = h2f(si.x), s23 = h2f(si.y);
    float4 o;
    o.x = fmaf(acc0, inv, s01.x);
    o.y = fmaf(acc1, inv, s01.y);
    o.z = fmaf(acc2, inv, s23.x);
    o.w = fmaf(acc3, inv, s23.y);
    if (lane < 8) outf4[(size_t)wid * 8 + j] = o;
}

// ---------------------------------------------------------------------------
extern "C" void kernel_launch(void* const* d_in, const int* in_sizes, int n_in,
                              void* d_out, int out_size, void* d_ws, size_t ws_size,
                              hipStream_t stream)
{
    const float* x   = (const float*)d_in[0];
    const int* ei    = (const int*)d_in[1];
    const float* Wq1 = (const float*)d_in[2];  const float* bq1 = (const float*)d_in[3];
    const float* Wk1 = (const float*)d_in[4];  const float* bk1 = (const float*)d_in[5];
    const float* Wv1 = (const float*)d_in[6];  const float* bv1 = (const float*)d_in[7];
    const float* Ws1 = (const float*)d_in[8];  const float* bs1 = (const float*)d_in[9];
    const float* Wq2 = (const float*)d_in[10]; const float* bq2 = (const float*)d_in[11];
    const float* Wk2 = (const float*)d_in[12]; const float* bk2 = (const float*)d_in[13];
    const float* Wv2 = (const float*)d_in[14]; const float* bv2 = (const float*)d_in[15];
    const float* Ws2 = (const float*)d_in[16]; const float* bs2 = (const float*)d_in[17];

    const int n = in_sizes[0] / 64;   // 50000
    const int e = in_sizes[1] / 2;    // 800000
    const int* src = ei;
    const int* dst = ei + e;

    // workspace layout (fp16 activations; layer-2 buffers NOT aliased)
    __half* q1  = (__half*)d_ws;                       // n*64
    __half* s1  = q1 + (size_t)n * 64;                 // n*64
    __half* kv1 = s1 + (size_t)n * 64;                 // n*128
    __half* q2  = kv1 + (size_t)n * 128;               // n*32
    __half* s2  = q2 + (size_t)n * 32;                 // n*32
    __half* kv2 = s2 + (size_t)n * 32;                 // n*64
    int*  cnt    = (int*)(kv2 + (size_t)n * 64);       // n
    int*  bucket = cnt + n;                            // n*BCAP
    const int nbins = (n + 255) >> 8;                  // 196
    int2* pairs  = (int2*)(bucket + (size_t)n * BCAP); // nbins*BIN_CAP int2
    int*  bincur = (int*)(pairs + (size_t)nbins * BIN_CAP);  // nbins

    float* out = (float*)d_out;
    const int nblk  = (e + CHUNK - 1) / CHUNK;         // 196
    const int nb_gemm = (n + 63) / 64;

    // ---- layer-1 GEMM (also inits bincur) ----
    gemm1<<<nb_gemm, 256, 0, stream>>>(
        x, n, Wq1, Wk1, Wv1, Ws1, bq1, bk1, bv1, bs1, q1, s1, kv1,
        bincur, nbins);

    // ---- adjacency build ----
    scatter_fused<<<nblk, 256, 0, stream>>>(src, dst, bincur, pairs, e, nbins);
    fine_bucket<<<nbins, 512, 0, stream>>>(pairs, bincur, cnt, bucket, n);

    // ---- fused layer-1 attention + layer-2 GEMM ----
    attn1_gemm2<<<nb_gemm, 1024, 0, stream>>>(
        q1, s1, (const int4*)kv1, cnt, bucket,
        Wq2, Wk2, Wv2, Ws2, bq2, bk2, bv2, bs2,
        q2, s2, kv2, n);

    // ---- layer-2 attention ----
    attn_h1<<<(n + 3) / 4, 256, 0, stream>>>(
        q2, s2, (const int4*)kv2, cnt, bucket, (float4*)out, n);
}